// Round 8
// baseline (604.175 us; speedup 1.0000x reference)
//
#include <hip/hip_runtime.h>
#include <hip/hip_bf16.h>
#include <cstdint>
#include <cstddef>

// ---------------------------------------------------------------------------
// GAT x3 + MLP head.
// GEMMs: MFMA bf16 (fp32 accum), 128xTN tile, XOR-swizzled LDS.
// Messages stored HALF-MAJOR bf16: Qu[half(2)][node][32 uints]. Aggregate
// block (grp,half) -> blockIdx&1 = half, so each XCD's gather working set is
// 12.8 MB (XCD round-robin heuristic; correctness unaffected if wrong).
// Wave = node: 2 edge-groups x 32 dims, 4 edges/iter (R5 loop shape).
// CSR build = 2-level bucket sort.
// ---------------------------------------------------------------------------

#define PA_CHUNK 4096
#define BKT_CAP  12288

using short8  = __attribute__((ext_vector_type(8))) short;
using ushort8 = __attribute__((ext_vector_type(8))) unsigned short;
using f32x4   = __attribute__((ext_vector_type(4))) float;

__device__ __forceinline__ ushort f2bf_rne(float f) {
  uint u = __float_as_uint(f);
  u += 0x7FFFu + ((u >> 16) & 1u);
  return (ushort)(u >> 16);
}

// ---------------- Phase A: scatter edges into coarse buckets ----------------
__global__ __launch_bounds__(256) void bucket_scatter_kernel(
    const int* __restrict__ src, const int* __restrict__ dst,
    int* __restrict__ bcount, uint* __restrict__ buckets, int E, int NB) {
  __shared__ int  hist[256];
  __shared__ int  base[256];
  __shared__ uint recs[PA_CHUNK];
  __shared__ ushort rb[PA_CHUNK];
  const int t = threadIdx.x;
  const int e0 = blockIdx.x * PA_CHUNK;
  const int nE = min(PA_CHUNK, E - e0);

  for (int i = t; i < 256; i += 256) hist[i] = 0;
  __syncthreads();
  for (int i = t; i < nE; i += 256) {
    int s = src[e0 + i], d = dst[e0 + i];
    int b = d >> 9;
    recs[i] = ((uint)s << 9) | (uint)(d & 511);
    rb[i] = (ushort)b;
    atomicAdd(&hist[b], 1);
  }
  __syncthreads();
  if (t < NB) base[t] = (hist[t] > 0) ? atomicAdd(&bcount[t], hist[t]) : 0;
  __syncthreads();
  for (int i = t; i < 256; i += 256) hist[i] = 0;
  __syncthreads();
  for (int i = t; i < nE; i += 256) {
    int b = rb[i];
    int r = atomicAdd(&hist[b], 1);
    int pos = base[b] + r;
    if (pos < BKT_CAP) buckets[(size_t)b * BKT_CAP + pos] = recs[i];
  }
}

__global__ __launch_bounds__(256) void scan_buckets_kernel(
    const int* __restrict__ bcount, int* __restrict__ bbase, int NB,
    int* __restrict__ row_ptr, int N, int E) {
  __shared__ int s[256];
  int t = threadIdx.x;
  int x = (t < NB) ? bcount[t] : 0;
  s[t] = x;
  __syncthreads();
  #pragma unroll
  for (int off = 1; off < 256; off <<= 1) {
    int v = (t >= off) ? s[t - off] : 0;
    __syncthreads();
    s[t] += v;
    __syncthreads();
  }
  if (t < NB) bbase[t] = s[t] - x;
  if (t == 0) row_ptr[N] = E;
}

__global__ __launch_bounds__(256) void bucket_sort_kernel(
    const uint* __restrict__ buckets, const int* __restrict__ bcount,
    const int* __restrict__ bbase, int* __restrict__ row_ptr,
    int* __restrict__ src_sorted, int N) {
  const int b = blockIdx.x;
  const int t = threadIdx.x;
  __shared__ int h[512], o[512], c[512];
  __shared__ int wsum[4];
  const int cnt = min(bcount[b], BKT_CAP);
  const int gbase = bbase[b];
  const uint* rec = buckets + (size_t)b * BKT_CAP;

  for (int i = t; i < 512; i += 256) { h[i] = 0; c[i] = 0; }
  __syncthreads();
  for (int i = t; i < cnt; i += 256) atomicAdd(&h[rec[i] & 511], 1);
  __syncthreads();

  int a0 = h[2 * t], a1 = h[2 * t + 1];
  int s2 = a0 + a1;
  int lane = t & 63, w = t >> 6;
  int v = s2;
  #pragma unroll
  for (int off = 1; off < 64; off <<= 1) {
    int u = __shfl_up(v, off, 64);
    if (lane >= off) v += u;
  }
  if (lane == 63) wsum[w] = v;
  __syncthreads();
  int woff = 0;
  for (int i = 0; i < w; ++i) woff += wsum[i];
  int excl = (v - s2) + woff;
  o[2 * t]     = excl;
  o[2 * t + 1] = excl + a0;
  __syncthreads();

  for (int i = t; i < 512; i += 256) {
    int node = (b << 9) + i;
    if (node < N) row_ptr[node] = gbase + o[i];
  }
  for (int i = t; i < cnt; i += 256) {
    uint r = rec[i];
    int d9 = r & 511;
    int rk = atomicAdd(&c[d9], 1);
    src_sorted[gbase + o[d9] + rk] = (int)(r >> 9);
  }
}

// ---------------- weight prep: Wt bf16, transposed + XOR-swizzled ----------------
__global__ __launch_bounds__(256) void wprep_kernel(const float* __restrict__ W,
                                                    ushort* __restrict__ Wt, int TN) {
  int idx = blockIdx.x * 256 + threadIdx.x;
  if (idx >= TN * 16) return;
  int n = idx % TN;
  int c = idx / TN;
  ushort8 o;
  #pragma unroll
  for (int j = 0; j < 8; ++j) o[j] = f2bf_rne(W[(c * 8 + j) * TN + n]);
  *(ushort8*)(Wt + n * 128 + ((c ^ (n & 7)) * 8)) = o;
}

// ---------------- MFMA GEMM: C[N,TN] = A[N,128] @ W[128,TN] ----------------
// OBF16: write half-major bf16 Qu[half][node][64 ushorts]; else row-major fp32.
template <int TN, bool RELU, bool HASBIAS, bool OBF16>
__global__ __launch_bounds__(256) void mfma_gemm_kernel(const float* __restrict__ A,
                                                        const ushort* __restrict__ Wt,
                                                        const float* __restrict__ bias,
                                                        void* __restrict__ Cv, int n) {
  constexpr int WCOLS = TN / 2;
  constexpr int FI = 4;
  constexpr int FJ = WCOLS / 16;
  __shared__ char lds[32768 + TN * 256];
  ushort* sA = (ushort*)lds;
  ushort* sW = (ushort*)(lds + 32768);

  const int t = threadIdx.x;
  const int row0 = blockIdx.x * 128;
  const int lane = t & 63;
  const int wid = t >> 6;
  const int wr = wid >> 1, wc = wid & 1;

  #pragma unroll
  for (int i = 0; i < 8; ++i) {
    int r = i * 16 + (t >> 4);
    int c = t & 15;
    int gr = row0 + r;
    float4 v0 = make_float4(0.f, 0.f, 0.f, 0.f), v1 = v0;
    if (gr < n) {
      const float4* Ar = (const float4*)(A + (size_t)gr * 128);
      v0 = Ar[c * 2];
      v1 = Ar[c * 2 + 1];
    }
    ushort8 o;
    o[0] = f2bf_rne(v0.x); o[1] = f2bf_rne(v0.y); o[2] = f2bf_rne(v0.z); o[3] = f2bf_rne(v0.w);
    o[4] = f2bf_rne(v1.x); o[5] = f2bf_rne(v1.y); o[6] = f2bf_rne(v1.z); o[7] = f2bf_rne(v1.w);
    *(ushort8*)(sA + r * 128 + ((c ^ (r & 7)) * 8)) = o;
  }
  #pragma unroll
  for (int i = 0; i < TN / 16; ++i) {
    int chunk = i * 256 + t;
    *(ushort8*)(sW + chunk * 8) = *(const ushort8*)(Wt + chunk * 8);
  }
  __syncthreads();

  f32x4 acc[FI][FJ] = {};
  const int lm = lane & 15, q = lane >> 4, l7 = lane & 7;

  #pragma unroll
  for (int kk = 0; kk < 4; ++kk) {
    const int cs = kk * 4 + q;
    short8 af[FI], bfr[FJ];
    #pragma unroll
    for (int i = 0; i < FI; ++i) {
      int r = wr * 64 + i * 16 + lm;
      af[i] = *(const short8*)(sA + r * 128 + ((cs ^ l7) * 8));
    }
    #pragma unroll
    for (int j = 0; j < FJ; ++j) {
      int nn = wc * WCOLS + j * 16 + lm;
      bfr[j] = *(const short8*)(sW + nn * 128 + ((cs ^ l7) * 8));
    }
    #pragma unroll
    for (int i = 0; i < FI; ++i)
      #pragma unroll
      for (int j = 0; j < FJ; ++j)
        acc[i][j] = __builtin_amdgcn_mfma_f32_16x16x32_bf16(af[i], bfr[j], acc[i][j], 0, 0, 0);
  }

  #pragma unroll
  for (int i = 0; i < FI; ++i) {
    #pragma unroll
    for (int j = 0; j < FJ; ++j) {
      int gcol = wc * WCOLS + j * 16 + lm;
      float bv = HASBIAS ? bias[gcol] : 0.f;
      #pragma unroll
      for (int r = 0; r < 4; ++r) {
        int grow = row0 + wr * 64 + i * 16 + q * 4 + r;
        if (grow < n) {
          float v = acc[i][j][r] + bv;
          if (RELU) v = fmaxf(v, 0.f);
          if (OBF16) {
            int half = gcol >> 6;
            ((ushort*)Cv)[((size_t)half * n + grow) * 64 + (gcol & 63)] = f2bf_rne(v);
          } else {
            ((float*)Cv)[(size_t)grow * TN + gcol] = v;
          }
        }
      }
    }
  }
}

// ---------------- vs/vd = W @ a (layer 1 dst path) ----------------
__global__ void make_v2_kernel(const float* __restrict__ Ws, const float* __restrict__ as_,
                               const float* __restrict__ Wd, const float* __restrict__ ad_,
                               float* __restrict__ vs, float* __restrict__ vd) {
  int gw = blockIdx.x * (blockDim.x >> 6) + (threadIdx.x >> 6);
  int lane = threadIdx.x & 63;
  int d = gw & 127;
  const float* W = (gw < 128) ? Ws : Wd;
  const float* a = (gw < 128) ? as_ : ad_;
  float2 w0 = ((const float2*)(W + d * 128))[lane];
  float2 a0 = ((const float2*)a)[lane];
  float p = w0.x * a0.x + w0.y * a0.y;
  #pragma unroll
  for (int off = 32; off >= 1; off >>= 1) p += __shfl_down(p, off, 64);
  if (lane == 0) ((gw < 128) ? vs : vd)[d] = p;
}

// ---------------- alpha from fp32 X (layer 1) ----------------
__global__ void alpha_kernel(const float* __restrict__ X, const float* __restrict__ vs,
                             const float* __restrict__ vd, float* __restrict__ as_,
                             float* __restrict__ ad_, int n) {
  int wid = blockIdx.x * (blockDim.x >> 6) + (threadIdx.x >> 6);
  int lane = threadIdx.x & 63;
  if (wid >= n) return;
  float2 xv = ((const float2*)X)[(size_t)wid * 64 + lane];
  float2 v1 = ((const float2*)vs)[lane];
  float2 v2 = ((const float2*)vd)[lane];
  float ps = xv.x * v1.x + xv.y * v1.y;
  float pd = xv.x * v2.x + xv.y * v2.y;
  #pragma unroll
  for (int off = 32; off > 0; off >>= 1) {
    ps += __shfl_down(ps, off, 64);
    pd += __shfl_down(pd, off, 64);
  }
  if (lane == 0) { as_[wid] = ps; ad_[wid] = pd; }
}

// ---------------- alpha from half-major bf16 hs (layers 2,3) ----------------
// uint for (node, lane): half = lane>>5, dp = lane&31; value-dim pair index
// half*32+dp == lane, so a_s/a_d float2 indexing by lane is unchanged.
__global__ void alphaQ_kernel(const uint* __restrict__ Qu, const float* __restrict__ a_s,
                              const float* __restrict__ a_d, float* __restrict__ as_,
                              float* __restrict__ ad_, int n) {
  int wid = blockIdx.x * (blockDim.x >> 6) + (threadIdx.x >> 6);
  int lane = threadIdx.x & 63;
  if (wid >= n) return;
  uint h = Qu[((size_t)(lane >> 5) * n + wid) * 32 + (lane & 31)];
  float hx = __uint_as_float(h << 16), hy = __uint_as_float(h & 0xFFFF0000u);
  float2 s2 = ((const float2*)a_s)[lane];
  float2 d2 = ((const float2*)a_d)[lane];
  float ps = hx * s2.x + hy * s2.y;
  float pd = hx * d2.x + hy * d2.y;
  #pragma unroll
  for (int off = 32; off > 0; off >>= 1) {
    ps += __shfl_down(ps, off, 64);
    pd += __shfl_down(pd, off, 64);
  }
  if (lane == 0) { as_[wid] = ps; ad_[wid] = pd; }
}

// ---------------- per-edge records: erec[j] = (src, exp(lrelu(as+ad))) ----------------
__global__ void edge_p_kernel(const int* __restrict__ row_ptr, const int* __restrict__ src_sorted,
                              const float* __restrict__ alpha_s, const float* __restrict__ alpha_d,
                              uint2* __restrict__ erec, int n) {
  int wid = blockIdx.x * (blockDim.x >> 6) + (threadIdx.x >> 6);
  int lane = threadIdx.x & 63;
  int node = wid * 4 + (lane >> 4);
  if (node >= n) return;
  int beg = row_ptr[node], end = row_ptr[node + 1];
  float ad = alpha_d[node];
  for (int j = beg + (lane & 15); j < end; j += 16) {
    int u = src_sorted[j];
    float e = alpha_s[u] + ad;
    e = (e > 0.f) ? e : 0.2f * e;
    erec[j] = make_uint2((uint)u, __float_as_uint(__expf(e)));
  }
}

// ---------------- GAT aggregation: half-split, wave per (node, half) ----------
// blockIdx = grp*2 + half; 64 lanes = 2 edge-groups x 32 uint-dims; 4 edges/iter.
__global__ void gat_aggregate_kernel(const uint* __restrict__ Qu,
                                     const uint2* __restrict__ erec,
                                     const int* __restrict__ row_ptr,
                                     const float* __restrict__ bias,
                                     float* __restrict__ out, int n) {
  const int b = blockIdx.x;
  const int half = b & 1;
  const int node = (b >> 1) * 4 + (threadIdx.x >> 6);
  if (node >= n) return;
  const int lane = threadIdx.x & 63;
  const int eg = lane >> 5, dp = lane & 31;
  const uint* Qh = Qu + (size_t)half * n * 32;
  const int beg = row_ptr[node], end = row_ptr[node + 1];
  float s01 = 0.f, s23 = 0.f;
  float x0 = 0.f, y0 = 0.f, x1 = 0.f, y1 = 0.f;
  int j = beg;
  for (; j + 4 <= end; j += 4) {
    uint2 r0 = erec[j + 0], r1 = erec[j + 1];
    uint2 r2 = erec[j + 2], r3 = erec[j + 3];
    uint  ua = eg ? r1.x : r0.x;
    uint  ub = eg ? r3.x : r2.x;
    float pa = __uint_as_float(eg ? r1.y : r0.y);
    float pb = __uint_as_float(eg ? r3.y : r2.y);
    uint ha = Qh[(size_t)ua * 32 + dp];
    uint hb = Qh[(size_t)ub * 32 + dp];
    s01 += __uint_as_float(r0.y) + __uint_as_float(r1.y);
    s23 += __uint_as_float(r2.y) + __uint_as_float(r3.y);
    x0 = fmaf(pa, __uint_as_float(ha << 16), x0);
    y0 = fmaf(pa, __uint_as_float(ha & 0xFFFF0000u), y0);
    x1 = fmaf(pb, __uint_as_float(hb << 16), x1);
    y1 = fmaf(pb, __uint_as_float(hb & 0xFFFF0000u), y1);
  }
  for (; j < end; j += 2) {
    uint2 ra = erec[j];
    bool has2 = (j + 1) < end;
    uint2 rb = has2 ? erec[j + 1] : make_uint2(0u, 0u);
    float pa_ = __uint_as_float(ra.y);
    float pb_ = has2 ? __uint_as_float(rb.y) : 0.f;
    s01 += pa_ + pb_;
    uint  ue = eg ? rb.x : ra.x;
    float pe = eg ? pb_ : pa_;
    uint he = Qh[(size_t)ue * 32 + dp];
    x0 = fmaf(pe, __uint_as_float(he << 16), x0);
    y0 = fmaf(pe, __uint_as_float(he & 0xFFFF0000u), y0);
  }
  float s = s01 + s23;                 // uniform across lanes
  float ax = x0 + x1, ay = y0 + y1;
  ax += __shfl_xor(ax, 32, 64);
  ay += __shfl_xor(ay, 32, 64);
  if (eg == 0) {
    float inv = 1.f / (s + 1e-16f);
    float2 bv = ((const float2*)bias)[half * 32 + dp];
    float2 o;
    o.x = fmaxf(fmaf(ax, inv, bv.x), 0.f);
    o.y = fmaxf(fmaf(ay, inv, bv.y), 0.f);
    ((float2*)out)[(size_t)node * 64 + half * 32 + dp] = o;
  }
}

// ---------------------------------------------------------------------------
extern "C" void kernel_launch(void* const* d_in, const int* in_sizes, int n_in,
                              void* d_out, int out_size, void* d_ws, size_t ws_size,
                              hipStream_t stream) {
  const float* x     = (const float*)d_in[0];
  const int*   eidx  = (const int*)d_in[1];
  const float* W1s   = (const float*)d_in[2];
  const float* W1d   = (const float*)d_in[3];
  const float* a1s   = (const float*)d_in[4];
  const float* a1d   = (const float*)d_in[5];
  const float* b1    = (const float*)d_in[6];
  const float* W2    = (const float*)d_in[7];
  const float* a2s   = (const float*)d_in[8];
  const float* a2d   = (const float*)d_in[9];
  const float* b2    = (const float*)d_in[10];
  const float* W3    = (const float*)d_in[11];
  const float* a3s   = (const float*)d_in[12];
  const float* a3d   = (const float*)d_in[13];
  const float* b3    = (const float*)d_in[14];
  const float* Wl1   = (const float*)d_in[15];
  const float* bl1   = (const float*)d_in[16];
  const float* Wl2   = (const float*)d_in[17];
  const float* bl2   = (const float*)d_in[18];
  float* out = (float*)d_out;

  const int N = in_sizes[0] / 128;
  const int E = in_sizes[1] / 2;
  const int* src = eidx;
  const int* dst = eidx + E;
  const int NB = (N + 511) >> 9;

  // ---- workspace layout ----
  char* base = (char*)d_ws;
  size_t off = 0;
  auto alloc = [&](size_t bytes) -> void* {
    void* p = base + off;
    off += (bytes + 511) & ~(size_t)511;
    return p;
  };
  float* P        = (float*)alloc((size_t)N * 128 * 4);  // layer io, fp32
  uint*  Qu       = (uint*)alloc((size_t)N * 128 * 2);   // messages, half-major bf16
  float* Q2       = (float*)alloc((size_t)N * 128 * 4);  // head hidden, fp32
  uint*  buckets  = (uint*)Q2;                           // alias: dead before head
  uint2* erec     = (uint2*)((char*)Q2 + ((size_t)24 << 20));  // alias: dead before head
  float* alpha_s  = (float*)alloc((size_t)N * 4);
  float* alpha_d  = (float*)alloc((size_t)N * 4);
  float* vs       = (float*)alloc(128 * 4);
  float* vd       = (float*)alloc(128 * 4);
  int* row_ptr    = (int*)alloc((size_t)(N + 1) * 4);
  int* bcount     = (int*)alloc(256 * 4);
  int* bbase      = (int*)alloc(256 * 4);
  int* src_sorted = (int*)alloc((size_t)E * 4);
  ushort* Wt1     = (ushort*)alloc(128 * 128 * 2);
  ushort* Wt2     = (ushort*)alloc(128 * 128 * 2);
  ushort* Wt3     = (ushort*)alloc(128 * 128 * 2);
  ushort* Wtl1    = (ushort*)alloc(128 * 128 * 2);
  ushort* Wtl2    = (ushort*)alloc(64 * 128 * 2);
  (void)ws_size;

  const int TB = 256;
  const int nwaveblk = (N + 3) / 4;
  const int ggrid = (N + 127) / 128;
  const int pagrid = (E + PA_CHUNK - 1) / PA_CHUNK;
  const int epgrid = (N + 15) / 16;
  const int aggrid = ((N + 3) / 4) * 2;

  // ---- CSR build ----
  hipMemsetAsync(bcount, 0, 256 * 4, stream);
  bucket_scatter_kernel<<<pagrid, 256, 0, stream>>>(src, dst, bcount, buckets, E, NB);
  scan_buckets_kernel<<<1, 256, 0, stream>>>(bcount, bbase, NB, row_ptr, N, E);
  bucket_sort_kernel<<<NB, 256, 0, stream>>>(buckets, bcount, bbase, row_ptr, src_sorted, N);

  // ---- weight prep ----
  wprep_kernel<<<8, 256, 0, stream>>>(W1s, Wt1, 128);
  wprep_kernel<<<8, 256, 0, stream>>>(W2,  Wt2, 128);
  wprep_kernel<<<8, 256, 0, stream>>>(W3,  Wt3, 128);
  wprep_kernel<<<8, 256, 0, stream>>>(Wl1, Wtl1, 128);
  wprep_kernel<<<4, 256, 0, stream>>>(Wl2, Wtl2, 64);

  // ---- layer 1: x -> P ----
  make_v2_kernel<<<64, 256, 0, stream>>>(W1s, a1s, W1d, a1d, vs, vd);
  alpha_kernel<<<nwaveblk, TB, 0, stream>>>(x, vs, vd, alpha_s, alpha_d, N);
  mfma_gemm_kernel<128, false, false, true><<<ggrid, 256, 0, stream>>>(x, Wt1, nullptr, Qu, N);
  edge_p_kernel<<<epgrid, TB, 0, stream>>>(row_ptr, src_sorted, alpha_s, alpha_d, erec, N);
  gat_aggregate_kernel<<<aggrid, TB, 0, stream>>>(Qu, erec, row_ptr, b1, P, N);

  // ---- layer 2: P -> P ----
  mfma_gemm_kernel<128, false, false, true><<<ggrid, 256, 0, stream>>>(P, Wt2, nullptr, Qu, N);
  alphaQ_kernel<<<nwaveblk, TB, 0, stream>>>(Qu, a2s, a2d, alpha_s, alpha_d, N);
  edge_p_kernel<<<epgrid, TB, 0, stream>>>(row_ptr, src_sorted, alpha_s, alpha_d, erec, N);
  gat_aggregate_kernel<<<aggrid, TB, 0, stream>>>(Qu, erec, row_ptr, b2, P, N);

  // ---- layer 3: P -> P ----
  mfma_gemm_kernel<128, false, false, true><<<ggrid, 256, 0, stream>>>(P, Wt3, nullptr, Qu, N);
  alphaQ_kernel<<<nwaveblk, TB, 0, stream>>>(Qu, a3s, a3d, alpha_s, alpha_d, N);
  edge_p_kernel<<<epgrid, TB, 0, stream>>>(row_ptr, src_sorted, alpha_s, alpha_d, erec, N);
  gat_aggregate_kernel<<<aggrid, TB, 0, stream>>>(Qu, erec, row_ptr, b3, P, N);

  // ---- MLP head (Q2 region free now) ----
  mfma_gemm_kernel<128, true, true, false><<<ggrid, 256, 0, stream>>>(P, Wtl1, bl1, Q2, N);
  mfma_gemm_kernel<64, false, true, false><<<ggrid, 256, 0, stream>>>(Q2, Wtl2, bl2, out, N);
}

// Round 9
// 446.174 us; speedup vs baseline: 1.3541x; 1.3541x over previous
//
#include <hip/hip_runtime.h>
#include <hip/hip_bf16.h>
#include <cstdint>
#include <cstddef>

// ---------------------------------------------------------------------------
// GAT x3 + MLP head.
// GEMMs: MFMA bf16 (fp32 accum), 128xTN tile, XOR-swizzled LDS.
// Messages row-major bf16. Aggregation: CSR-by-dst, one wave per node,
// 64 lanes x 2 dims, 8 edges in flight (4 x uint4 erec + 8 h gathers),
// 4 accumulator chains. CSR build = 2-level bucket sort.
// ---------------------------------------------------------------------------

#define PA_CHUNK 4096
#define BKT_CAP  12288

using short8  = __attribute__((ext_vector_type(8))) short;
using ushort8 = __attribute__((ext_vector_type(8))) unsigned short;
using f32x4   = __attribute__((ext_vector_type(4))) float;

__device__ __forceinline__ ushort f2bf_rne(float f) {
  uint u = __float_as_uint(f);
  u += 0x7FFFu + ((u >> 16) & 1u);
  return (ushort)(u >> 16);
}

// ---------------- Phase A: scatter edges into coarse buckets ----------------
__global__ __launch_bounds__(256) void bucket_scatter_kernel(
    const int* __restrict__ src, const int* __restrict__ dst,
    int* __restrict__ bcount, uint* __restrict__ buckets, int E, int NB) {
  __shared__ int  hist[256];
  __shared__ int  base[256];
  __shared__ uint recs[PA_CHUNK];
  __shared__ ushort rb[PA_CHUNK];
  const int t = threadIdx.x;
  const int e0 = blockIdx.x * PA_CHUNK;
  const int nE = min(PA_CHUNK, E - e0);

  for (int i = t; i < 256; i += 256) hist[i] = 0;
  __syncthreads();
  for (int i = t; i < nE; i += 256) {
    int s = src[e0 + i], d = dst[e0 + i];
    int b = d >> 9;
    recs[i] = ((uint)s << 9) | (uint)(d & 511);
    rb[i] = (ushort)b;
    atomicAdd(&hist[b], 1);
  }
  __syncthreads();
  if (t < NB) base[t] = (hist[t] > 0) ? atomicAdd(&bcount[t], hist[t]) : 0;
  __syncthreads();
  for (int i = t; i < 256; i += 256) hist[i] = 0;
  __syncthreads();
  for (int i = t; i < nE; i += 256) {
    int b = rb[i];
    int r = atomicAdd(&hist[b], 1);
    int pos = base[b] + r;
    if (pos < BKT_CAP) buckets[(size_t)b * BKT_CAP + pos] = recs[i];
  }
}

__global__ __launch_bounds__(256) void scan_buckets_kernel(
    const int* __restrict__ bcount, int* __restrict__ bbase, int NB,
    int* __restrict__ row_ptr, int N, int E) {
  __shared__ int s[256];
  int t = threadIdx.x;
  int x = (t < NB) ? bcount[t] : 0;
  s[t] = x;
  __syncthreads();
  #pragma unroll
  for (int off = 1; off < 256; off <<= 1) {
    int v = (t >= off) ? s[t - off] : 0;
    __syncthreads();
    s[t] += v;
    __syncthreads();
  }
  if (t < NB) bbase[t] = s[t] - x;
  if (t == 0) row_ptr[N] = E;
}

__global__ __launch_bounds__(256) void bucket_sort_kernel(
    const uint* __restrict__ buckets, const int* __restrict__ bcount,
    const int* __restrict__ bbase, int* __restrict__ row_ptr,
    int* __restrict__ src_sorted, int N) {
  const int b = blockIdx.x;
  const int t = threadIdx.x;
  __shared__ int h[512], o[512], c[512];
  __shared__ int wsum[4];
  const int cnt = min(bcount[b], BKT_CAP);
  const int gbase = bbase[b];
  const uint* rec = buckets + (size_t)b * BKT_CAP;

  for (int i = t; i < 512; i += 256) { h[i] = 0; c[i] = 0; }
  __syncthreads();
  for (int i = t; i < cnt; i += 256) atomicAdd(&h[rec[i] & 511], 1);
  __syncthreads();

  int a0 = h[2 * t], a1 = h[2 * t + 1];
  int s2 = a0 + a1;
  int lane = t & 63, w = t >> 6;
  int v = s2;
  #pragma unroll
  for (int off = 1; off < 64; off <<= 1) {
    int u = __shfl_up(v, off, 64);
    if (lane >= off) v += u;
  }
  if (lane == 63) wsum[w] = v;
  __syncthreads();
  int woff = 0;
  for (int i = 0; i < w; ++i) woff += wsum[i];
  int excl = (v - s2) + woff;
  o[2 * t]     = excl;
  o[2 * t + 1] = excl + a0;
  __syncthreads();

  for (int i = t; i < 512; i += 256) {
    int node = (b << 9) + i;
    if (node < N) row_ptr[node] = gbase + o[i];
  }
  for (int i = t; i < cnt; i += 256) {
    uint r = rec[i];
    int d9 = r & 511;
    int rk = atomicAdd(&c[d9], 1);
    src_sorted[gbase + o[d9] + rk] = (int)(r >> 9);
  }
}

// ---------------- weight prep: Wt bf16, transposed + XOR-swizzled ----------------
__global__ __launch_bounds__(256) void wprep_kernel(const float* __restrict__ W,
                                                    ushort* __restrict__ Wt, int TN) {
  int idx = blockIdx.x * 256 + threadIdx.x;
  if (idx >= TN * 16) return;
  int n = idx % TN;
  int c = idx / TN;
  ushort8 o;
  #pragma unroll
  for (int j = 0; j < 8; ++j) o[j] = f2bf_rne(W[(c * 8 + j) * TN + n]);
  *(ushort8*)(Wt + n * 128 + ((c ^ (n & 7)) * 8)) = o;
}

// ---------------- MFMA GEMM: C[N,TN] = A[N,128] @ W[128,TN] ----------------
template <int TN, bool RELU, bool HASBIAS, bool OBF16>
__global__ __launch_bounds__(256) void mfma_gemm_kernel(const float* __restrict__ A,
                                                        const ushort* __restrict__ Wt,
                                                        const float* __restrict__ bias,
                                                        void* __restrict__ Cv, int n) {
  constexpr int WCOLS = TN / 2;
  constexpr int FI = 4;
  constexpr int FJ = WCOLS / 16;
  __shared__ char lds[32768 + TN * 256];
  ushort* sA = (ushort*)lds;
  ushort* sW = (ushort*)(lds + 32768);

  const int t = threadIdx.x;
  const int row0 = blockIdx.x * 128;
  const int lane = t & 63;
  const int wid = t >> 6;
  const int wr = wid >> 1, wc = wid & 1;

  #pragma unroll
  for (int i = 0; i < 8; ++i) {
    int r = i * 16 + (t >> 4);
    int c = t & 15;
    int gr = row0 + r;
    float4 v0 = make_float4(0.f, 0.f, 0.f, 0.f), v1 = v0;
    if (gr < n) {
      const float4* Ar = (const float4*)(A + (size_t)gr * 128);
      v0 = Ar[c * 2];
      v1 = Ar[c * 2 + 1];
    }
    ushort8 o;
    o[0] = f2bf_rne(v0.x); o[1] = f2bf_rne(v0.y); o[2] = f2bf_rne(v0.z); o[3] = f2bf_rne(v0.w);
    o[4] = f2bf_rne(v1.x); o[5] = f2bf_rne(v1.y); o[6] = f2bf_rne(v1.z); o[7] = f2bf_rne(v1.w);
    *(ushort8*)(sA + r * 128 + ((c ^ (r & 7)) * 8)) = o;
  }
  #pragma unroll
  for (int i = 0; i < TN / 16; ++i) {
    int chunk = i * 256 + t;
    *(ushort8*)(sW + chunk * 8) = *(const ushort8*)(Wt + chunk * 8);
  }
  __syncthreads();

  f32x4 acc[FI][FJ] = {};
  const int lm = lane & 15, q = lane >> 4, l7 = lane & 7;

  #pragma unroll
  for (int kk = 0; kk < 4; ++kk) {
    const int cs = kk * 4 + q;
    short8 af[FI], bfr[FJ];
    #pragma unroll
    for (int i = 0; i < FI; ++i) {
      int r = wr * 64 + i * 16 + lm;
      af[i] = *(const short8*)(sA + r * 128 + ((cs ^ l7) * 8));
    }
    #pragma unroll
    for (int j = 0; j < FJ; ++j) {
      int nn = wc * WCOLS + j * 16 + lm;
      bfr[j] = *(const short8*)(sW + nn * 128 + ((cs ^ l7) * 8));
    }
    #pragma unroll
    for (int i = 0; i < FI; ++i)
      #pragma unroll
      for (int j = 0; j < FJ; ++j)
        acc[i][j] = __builtin_amdgcn_mfma_f32_16x16x32_bf16(af[i], bfr[j], acc[i][j], 0, 0, 0);
  }

  #pragma unroll
  for (int i = 0; i < FI; ++i) {
    #pragma unroll
    for (int j = 0; j < FJ; ++j) {
      int gcol = wc * WCOLS + j * 16 + lm;
      float bv = HASBIAS ? bias[gcol] : 0.f;
      #pragma unroll
      for (int r = 0; r < 4; ++r) {
        int grow = row0 + wr * 64 + i * 16 + q * 4 + r;
        if (grow < n) {
          float v = acc[i][j][r] + bv;
          if (RELU) v = fmaxf(v, 0.f);
          if (OBF16) ((ushort*)Cv)[(size_t)grow * TN + gcol] = f2bf_rne(v);
          else       ((float*)Cv)[(size_t)grow * TN + gcol] = v;
        }
      }
    }
  }
}

// ---------------- vs/vd = W @ a (layer 1 dst path) ----------------
__global__ void make_v2_kernel(const float* __restrict__ Ws, const float* __restrict__ as_,
                               const float* __restrict__ Wd, const float* __restrict__ ad_,
                               float* __restrict__ vs, float* __restrict__ vd) {
  int gw = blockIdx.x * (blockDim.x >> 6) + (threadIdx.x >> 6);
  int lane = threadIdx.x & 63;
  int d = gw & 127;
  const float* W = (gw < 128) ? Ws : Wd;
  const float* a = (gw < 128) ? as_ : ad_;
  float2 w0 = ((const float2*)(W + d * 128))[lane];
  float2 a0 = ((const float2*)a)[lane];
  float p = w0.x * a0.x + w0.y * a0.y;
  #pragma unroll
  for (int off = 32; off >= 1; off >>= 1) p += __shfl_down(p, off, 64);
  if (lane == 0) ((gw < 128) ? vs : vd)[d] = p;
}

// ---------------- alpha from fp32 X (layer 1) ----------------
__global__ void alpha_kernel(const float* __restrict__ X, const float* __restrict__ vs,
                             const float* __restrict__ vd, float* __restrict__ as_,
                             float* __restrict__ ad_, int n) {
  int wid = blockIdx.x * (blockDim.x >> 6) + (threadIdx.x >> 6);
  int lane = threadIdx.x & 63;
  if (wid >= n) return;
  float2 xv = ((const float2*)X)[(size_t)wid * 64 + lane];
  float2 v1 = ((const float2*)vs)[lane];
  float2 v2 = ((const float2*)vd)[lane];
  float ps = xv.x * v1.x + xv.y * v1.y;
  float pd = xv.x * v2.x + xv.y * v2.y;
  #pragma unroll
  for (int off = 32; off > 0; off >>= 1) {
    ps += __shfl_down(ps, off, 64);
    pd += __shfl_down(pd, off, 64);
  }
  if (lane == 0) { as_[wid] = ps; ad_[wid] = pd; }
}

// ---------------- alpha from row-major bf16 hs (layers 2,3) ----------------
__global__ void alphaQ_kernel(const uint* __restrict__ hsb, const float* __restrict__ a_s,
                              const float* __restrict__ a_d, float* __restrict__ as_,
                              float* __restrict__ ad_, int n) {
  int wid = blockIdx.x * (blockDim.x >> 6) + (threadIdx.x >> 6);
  int lane = threadIdx.x & 63;
  if (wid >= n) return;
  uint h = hsb[(size_t)wid * 64 + lane];
  float hx = __uint_as_float(h << 16), hy = __uint_as_float(h & 0xFFFF0000u);
  float2 s2 = ((const float2*)a_s)[lane];
  float2 d2 = ((const float2*)a_d)[lane];
  float ps = hx * s2.x + hy * s2.y;
  float pd = hx * d2.x + hy * d2.y;
  #pragma unroll
  for (int off = 32; off > 0; off >>= 1) {
    ps += __shfl_down(ps, off, 64);
    pd += __shfl_down(pd, off, 64);
  }
  if (lane == 0) { as_[wid] = ps; ad_[wid] = pd; }
}

// ---------------- per-edge records: erec[j] = (src, exp(lrelu(as+ad))) ----------------
__global__ void edge_p_kernel(const int* __restrict__ row_ptr, const int* __restrict__ src_sorted,
                              const float* __restrict__ alpha_s, const float* __restrict__ alpha_d,
                              uint2* __restrict__ erec, int n) {
  int wid = blockIdx.x * (blockDim.x >> 6) + (threadIdx.x >> 6);
  int lane = threadIdx.x & 63;
  int node = wid * 4 + (lane >> 4);
  if (node >= n) return;
  int beg = row_ptr[node], end = row_ptr[node + 1];
  float ad = alpha_d[node];
  for (int j = beg + (lane & 15); j < end; j += 16) {
    int u = src_sorted[j];
    float e = alpha_s[u] + ad;
    e = (e > 0.f) ? e : 0.2f * e;
    erec[j] = make_uint2((uint)u, __float_as_uint(__expf(e)));
  }
}

// ---------------- GAT aggregation: one wave per node, 8 edges in flight ----------
__global__ void gat_aggregate_kernel(const uint* __restrict__ hsb,
                                     const uint2* __restrict__ erec,
                                     const int* __restrict__ row_ptr,
                                     const float* __restrict__ bias,
                                     float* __restrict__ out, int n) {
  int wid = blockIdx.x * (blockDim.x >> 6) + (threadIdx.x >> 6);
  int lane = threadIdx.x & 63;
  if (wid >= n) return;
  int beg = row_ptr[wid], end = row_ptr[wid + 1];
  float s0 = 0.f, s1 = 0.f, s2 = 0.f, s3 = 0.f;
  float a0x = 0.f, a0y = 0.f, a1x = 0.f, a1y = 0.f;
  float a2x = 0.f, a2y = 0.f, a3x = 0.f, a3y = 0.f;
  int j = beg;
  for (; j + 8 <= end; j += 8) {
    // 4 x 16B erec loads (8 records) + 8 independent h gathers, all in flight
    uint4 e01 = *(const uint4*)&erec[j + 0];
    uint4 e23 = *(const uint4*)&erec[j + 2];
    uint4 e45 = *(const uint4*)&erec[j + 4];
    uint4 e67 = *(const uint4*)&erec[j + 6];
    uint h0 = hsb[(size_t)e01.x * 64 + lane];
    uint h1 = hsb[(size_t)e01.z * 64 + lane];
    uint h2 = hsb[(size_t)e23.x * 64 + lane];
    uint h3 = hsb[(size_t)e23.z * 64 + lane];
    uint h4 = hsb[(size_t)e45.x * 64 + lane];
    uint h5 = hsb[(size_t)e45.z * 64 + lane];
    uint h6 = hsb[(size_t)e67.x * 64 + lane];
    uint h7 = hsb[(size_t)e67.z * 64 + lane];
    float p0 = __uint_as_float(e01.y), p1 = __uint_as_float(e01.w);
    float p2 = __uint_as_float(e23.y), p3 = __uint_as_float(e23.w);
    float p4 = __uint_as_float(e45.y), p5 = __uint_as_float(e45.w);
    float p6 = __uint_as_float(e67.y), p7 = __uint_as_float(e67.w);
    s0 += p0; a0x = fmaf(p0, __uint_as_float(h0 << 16), a0x); a0y = fmaf(p0, __uint_as_float(h0 & 0xFFFF0000u), a0y);
    s1 += p1; a1x = fmaf(p1, __uint_as_float(h1 << 16), a1x); a1y = fmaf(p1, __uint_as_float(h1 & 0xFFFF0000u), a1y);
    s2 += p2; a2x = fmaf(p2, __uint_as_float(h2 << 16), a2x); a2y = fmaf(p2, __uint_as_float(h2 & 0xFFFF0000u), a2y);
    s3 += p3; a3x = fmaf(p3, __uint_as_float(h3 << 16), a3x); a3y = fmaf(p3, __uint_as_float(h3 & 0xFFFF0000u), a3y);
    s0 += p4; a0x = fmaf(p4, __uint_as_float(h4 << 16), a0x); a0y = fmaf(p4, __uint_as_float(h4 & 0xFFFF0000u), a0y);
    s1 += p5; a1x = fmaf(p5, __uint_as_float(h5 << 16), a1x); a1y = fmaf(p5, __uint_as_float(h5 & 0xFFFF0000u), a1y);
    s2 += p6; a2x = fmaf(p6, __uint_as_float(h6 << 16), a2x); a2y = fmaf(p6, __uint_as_float(h6 & 0xFFFF0000u), a2y);
    s3 += p7; a3x = fmaf(p7, __uint_as_float(h7 << 16), a3x); a3y = fmaf(p7, __uint_as_float(h7 & 0xFFFF0000u), a3y);
  }
  for (; j + 4 <= end; j += 4) {
    uint4 e01 = *(const uint4*)&erec[j + 0];
    uint4 e23 = *(const uint4*)&erec[j + 2];
    uint h0 = hsb[(size_t)e01.x * 64 + lane];
    uint h1 = hsb[(size_t)e01.z * 64 + lane];
    uint h2 = hsb[(size_t)e23.x * 64 + lane];
    uint h3 = hsb[(size_t)e23.z * 64 + lane];
    float p0 = __uint_as_float(e01.y), p1 = __uint_as_float(e01.w);
    float p2 = __uint_as_float(e23.y), p3 = __uint_as_float(e23.w);
    s0 += p0; a0x = fmaf(p0, __uint_as_float(h0 << 16), a0x); a0y = fmaf(p0, __uint_as_float(h0 & 0xFFFF0000u), a0y);
    s1 += p1; a1x = fmaf(p1, __uint_as_float(h1 << 16), a1x); a1y = fmaf(p1, __uint_as_float(h1 & 0xFFFF0000u), a1y);
    s2 += p2; a2x = fmaf(p2, __uint_as_float(h2 << 16), a2x); a2y = fmaf(p2, __uint_as_float(h2 & 0xFFFF0000u), a2y);
    s3 += p3; a3x = fmaf(p3, __uint_as_float(h3 << 16), a3x); a3y = fmaf(p3, __uint_as_float(h3 & 0xFFFF0000u), a3y);
  }
  for (; j < end; ++j) {
    uint2 r0 = erec[j];
    float p0 = __uint_as_float(r0.y);
    uint h0 = hsb[(size_t)r0.x * 64 + lane];
    s0 += p0; a0x = fmaf(p0, __uint_as_float(h0 << 16), a0x); a0y = fmaf(p0, __uint_as_float(h0 & 0xFFFF0000u), a0y);
  }
  float s = (s0 + s1) + (s2 + s3);
  float ax = (a0x + a1x) + (a2x + a3x);
  float ay = (a0y + a1y) + (a2y + a3y);
  float inv = 1.f / (s + 1e-16f);
  float2 b = ((const float2*)bias)[lane];
  float o0 = fmaxf(fmaf(ax, inv, b.x), 0.f);
  float o1 = fmaxf(fmaf(ay, inv, b.y), 0.f);
  ((float2*)out)[(size_t)wid * 64 + lane] = make_float2(o0, o1);
}

// ---------------------------------------------------------------------------
extern "C" void kernel_launch(void* const* d_in, const int* in_sizes, int n_in,
                              void* d_out, int out_size, void* d_ws, size_t ws_size,
                              hipStream_t stream) {
  const float* x     = (const float*)d_in[0];
  const int*   eidx  = (const int*)d_in[1];
  const float* W1s   = (const float*)d_in[2];
  const float* W1d   = (const float*)d_in[3];
  const float* a1s   = (const float*)d_in[4];
  const float* a1d   = (const float*)d_in[5];
  const float* b1    = (const float*)d_in[6];
  const float* W2    = (const float*)d_in[7];
  const float* a2s   = (const float*)d_in[8];
  const float* a2d   = (const float*)d_in[9];
  const float* b2    = (const float*)d_in[10];
  const float* W3    = (const float*)d_in[11];
  const float* a3s   = (const float*)d_in[12];
  const float* a3d   = (const float*)d_in[13];
  const float* b3    = (const float*)d_in[14];
  const float* Wl1   = (const float*)d_in[15];
  const float* bl1   = (const float*)d_in[16];
  const float* Wl2   = (const float*)d_in[17];
  const float* bl2   = (const float*)d_in[18];
  float* out = (float*)d_out;

  const int N = in_sizes[0] / 128;
  const int E = in_sizes[1] / 2;
  const int* src = eidx;
  const int* dst = eidx + E;
  const int NB = (N + 511) >> 9;

  // ---- workspace layout ----
  char* base = (char*)d_ws;
  size_t off = 0;
  auto alloc = [&](size_t bytes) -> void* {
    void* p = base + off;
    off += (bytes + 511) & ~(size_t)511;
    return p;
  };
  float* P        = (float*)alloc((size_t)N * 128 * 4);  // layer io, fp32
  uint*  Qb       = (uint*)alloc((size_t)N * 128 * 2);   // messages, row-major bf16
  float* Q2       = (float*)alloc((size_t)N * 128 * 4);  // head hidden, fp32
  uint*  buckets  = (uint*)Q2;                           // alias: dead before head
  uint2* erec     = (uint2*)((char*)Q2 + ((size_t)24 << 20));  // alias: dead before head
  float* alpha_s  = (float*)alloc((size_t)N * 4);
  float* alpha_d  = (float*)alloc((size_t)N * 4);
  float* vs       = (float*)alloc(128 * 4);
  float* vd       = (float*)alloc(128 * 4);
  int* row_ptr    = (int*)alloc((size_t)(N + 1) * 4);
  int* bcount     = (int*)alloc(256 * 4);
  int* bbase      = (int*)alloc(256 * 4);
  int* src_sorted = (int*)alloc((size_t)E * 4);
  ushort* Wt1     = (ushort*)alloc(128 * 128 * 2);
  ushort* Wt2     = (ushort*)alloc(128 * 128 * 2);
  ushort* Wt3     = (ushort*)alloc(128 * 128 * 2);
  ushort* Wtl1    = (ushort*)alloc(128 * 128 * 2);
  ushort* Wtl2    = (ushort*)alloc(64 * 128 * 2);
  (void)ws_size;

  const int TB = 256;
  const int nwaveblk = (N + 3) / 4;
  const int ggrid = (N + 127) / 128;
  const int pagrid = (E + PA_CHUNK - 1) / PA_CHUNK;
  const int epgrid = (N + 15) / 16;

  // ---- CSR build ----
  hipMemsetAsync(bcount, 0, 256 * 4, stream);
  bucket_scatter_kernel<<<pagrid, 256, 0, stream>>>(src, dst, bcount, buckets, E, NB);
  scan_buckets_kernel<<<1, 256, 0, stream>>>(bcount, bbase, NB, row_ptr, N, E);
  bucket_sort_kernel<<<NB, 256, 0, stream>>>(buckets, bcount, bbase, row_ptr, src_sorted, N);

  // ---- weight prep ----
  wprep_kernel<<<8, 256, 0, stream>>>(W1s, Wt1, 128);
  wprep_kernel<<<8, 256, 0, stream>>>(W2,  Wt2, 128);
  wprep_kernel<<<8, 256, 0, stream>>>(W3,  Wt3, 128);
  wprep_kernel<<<8, 256, 0, stream>>>(Wl1, Wtl1, 128);
  wprep_kernel<<<4, 256, 0, stream>>>(Wl2, Wtl2, 64);

  // ---- layer 1: x -> P ----
  make_v2_kernel<<<64, 256, 0, stream>>>(W1s, a1s, W1d, a1d, vs, vd);
  alpha_kernel<<<nwaveblk, TB, 0, stream>>>(x, vs, vd, alpha_s, alpha_d, N);
  mfma_gemm_kernel<128, false, false, true><<<ggrid, 256, 0, stream>>>(x, Wt1, nullptr, Qb, N);
  edge_p_kernel<<<epgrid, TB, 0, stream>>>(row_ptr, src_sorted, alpha_s, alpha_d, erec, N);
  gat_aggregate_kernel<<<nwaveblk, TB, 0, stream>>>(Qb, erec, row_ptr, b1, P, N);

  // ---- layer 2: P -> P ----
  mfma_gemm_kernel<128, false, false, true><<<ggrid, 256, 0, stream>>>(P, Wt2, nullptr, Qb, N);
  alphaQ_kernel<<<nwaveblk, TB, 0, stream>>>(Qb, a2s, a2d, alpha_s, alpha_d, N);
  edge_p_kernel<<<epgrid, TB, 0, stream>>>(row_ptr, src_sorted, alpha_s, alpha_d, erec, N);
  gat_aggregate_kernel<<<nwaveblk, TB, 0, stream>>>(Qb, erec, row_ptr, b2, P, N);

  // ---- layer 3: P -> P ----
  mfma_gemm_kernel<128, false, false, true><<<ggrid, 256, 0, stream>>>(P, Wt3, nullptr, Qb, N);
  alphaQ_kernel<<<nwaveblk, TB, 0, stream>>>(Qb, a3s, a3d, alpha_s, alpha_d, N);
  edge_p_kernel<<<epgrid, TB, 0, stream>>>(row_ptr, src_sorted, alpha_s, alpha_d, erec, N);
  gat_aggregate_kernel<<<nwaveblk, TB, 0, stream>>>(Qb, erec, row_ptr, b3, P, N);

  // ---- MLP head (Q2 region free now) ----
  mfma_gemm_kernel<128, true, true, false><<<ggrid, 256, 0, stream>>>(P, Wtl1, bl1, Q2, N);
  mfma_gemm_kernel<64, false, true, false><<<ggrid, 256, 0, stream>>>(Q2, Wtl2, bl2, out, N);
}

// Round 10
// 421.456 us; speedup vs baseline: 1.4335x; 1.0586x over previous
//
#include <hip/hip_runtime.h>
#include <hip/hip_bf16.h>
#include <cstdint>
#include <cstddef>

// ---------------------------------------------------------------------------
// GAT x3 + MLP head.
// GEMMs: MFMA bf16 (fp32 accum), 128xTN tile, XOR-swizzled LDS.
// All inter-kernel tensors bf16 (numerically free: consumers round to bf16
// in staging anyway). Aggregation: CSR-by-dst, one wave per node, 8 edges in
// flight, 4 accumulator chains. CSR build = 2-level bucket sort.
// ---------------------------------------------------------------------------

#define PA_CHUNK 4096
#define BKT_CAP  12288

using short8  = __attribute__((ext_vector_type(8))) short;
using ushort8 = __attribute__((ext_vector_type(8))) unsigned short;
using f32x4   = __attribute__((ext_vector_type(4))) float;

__device__ __forceinline__ ushort f2bf_rne(float f) {
  uint u = __float_as_uint(f);
  u += 0x7FFFu + ((u >> 16) & 1u);
  return (ushort)(u >> 16);
}

// ---------------- Phase A: scatter edges into coarse buckets ----------------
__global__ __launch_bounds__(256) void bucket_scatter_kernel(
    const int* __restrict__ src, const int* __restrict__ dst,
    int* __restrict__ bcount, uint* __restrict__ buckets, int E, int NB) {
  __shared__ int  hist[256];
  __shared__ int  base[256];
  __shared__ uint recs[PA_CHUNK];
  __shared__ ushort rb[PA_CHUNK];
  const int t = threadIdx.x;
  const int e0 = blockIdx.x * PA_CHUNK;
  const int nE = min(PA_CHUNK, E - e0);

  for (int i = t; i < 256; i += 256) hist[i] = 0;
  __syncthreads();
  for (int i = t; i < nE; i += 256) {
    int s = src[e0 + i], d = dst[e0 + i];
    int b = d >> 9;
    recs[i] = ((uint)s << 9) | (uint)(d & 511);
    rb[i] = (ushort)b;
    atomicAdd(&hist[b], 1);
  }
  __syncthreads();
  if (t < NB) base[t] = (hist[t] > 0) ? atomicAdd(&bcount[t], hist[t]) : 0;
  __syncthreads();
  for (int i = t; i < 256; i += 256) hist[i] = 0;
  __syncthreads();
  for (int i = t; i < nE; i += 256) {
    int b = rb[i];
    int r = atomicAdd(&hist[b], 1);
    int pos = base[b] + r;
    if (pos < BKT_CAP) buckets[(size_t)b * BKT_CAP + pos] = recs[i];
  }
}

__global__ __launch_bounds__(256) void scan_buckets_kernel(
    const int* __restrict__ bcount, int* __restrict__ bbase, int NB,
    int* __restrict__ row_ptr, int N, int E) {
  __shared__ int s[256];
  int t = threadIdx.x;
  int x = (t < NB) ? bcount[t] : 0;
  s[t] = x;
  __syncthreads();
  #pragma unroll
  for (int off = 1; off < 256; off <<= 1) {
    int v = (t >= off) ? s[t - off] : 0;
    __syncthreads();
    s[t] += v;
    __syncthreads();
  }
  if (t < NB) bbase[t] = s[t] - x;
  if (t == 0) row_ptr[N] = E;
}

__global__ __launch_bounds__(256) void bucket_sort_kernel(
    const uint* __restrict__ buckets, const int* __restrict__ bcount,
    const int* __restrict__ bbase, int* __restrict__ row_ptr,
    int* __restrict__ src_sorted, int N) {
  const int b = blockIdx.x;
  const int t = threadIdx.x;
  __shared__ int h[512], o[512], c[512];
  __shared__ int wsum[4];
  const int cnt = min(bcount[b], BKT_CAP);
  const int gbase = bbase[b];
  const uint* rec = buckets + (size_t)b * BKT_CAP;

  for (int i = t; i < 512; i += 256) { h[i] = 0; c[i] = 0; }
  __syncthreads();
  for (int i = t; i < cnt; i += 256) atomicAdd(&h[rec[i] & 511], 1);
  __syncthreads();

  int a0 = h[2 * t], a1 = h[2 * t + 1];
  int s2 = a0 + a1;
  int lane = t & 63, w = t >> 6;
  int v = s2;
  #pragma unroll
  for (int off = 1; off < 64; off <<= 1) {
    int u = __shfl_up(v, off, 64);
    if (lane >= off) v += u;
  }
  if (lane == 63) wsum[w] = v;
  __syncthreads();
  int woff = 0;
  for (int i = 0; i < w; ++i) woff += wsum[i];
  int excl = (v - s2) + woff;
  o[2 * t]     = excl;
  o[2 * t + 1] = excl + a0;
  __syncthreads();

  for (int i = t; i < 512; i += 256) {
    int node = (b << 9) + i;
    if (node < N) row_ptr[node] = gbase + o[i];
  }
  for (int i = t; i < cnt; i += 256) {
    uint r = rec[i];
    int d9 = r & 511;
    int rk = atomicAdd(&c[d9], 1);
    src_sorted[gbase + o[d9] + rk] = (int)(r >> 9);
  }
}

// ---------------- weight prep (all 5 weights, one launch) ----------------
// Wt layout: row n, 16 chunks of 8 bf16; chunk c at (c ^ (n&7)); elem j = W[(c*8+j)*TN+n].
__device__ __forceinline__ void wprep_one(const float* __restrict__ W,
                                          ushort* __restrict__ Wt, int TN, int local) {
  int n = local % TN;
  int c = local / TN;
  ushort8 o;
  #pragma unroll
  for (int j = 0; j < 8; ++j) o[j] = f2bf_rne(W[(c * 8 + j) * TN + n]);
  *(ushort8*)(Wt + n * 128 + ((c ^ (n & 7)) * 8)) = o;
}

__global__ __launch_bounds__(256) void wprep_all_kernel(
    const float* __restrict__ W1s, const float* __restrict__ W2,
    const float* __restrict__ W3,  const float* __restrict__ Wl1,
    const float* __restrict__ Wl2,
    ushort* __restrict__ Wt1, ushort* __restrict__ Wt2, ushort* __restrict__ Wt3,
    ushort* __restrict__ Wtl1, ushort* __restrict__ Wtl2) {
  int idx = blockIdx.x * 256 + threadIdx.x;   // 0..9215
  if (idx < 2048)        wprep_one(W1s, Wt1, 128, idx);
  else if (idx < 4096)   wprep_one(W2,  Wt2, 128, idx - 2048);
  else if (idx < 6144)   wprep_one(W3,  Wt3, 128, idx - 4096);
  else if (idx < 8192)   wprep_one(Wl1, Wtl1, 128, idx - 6144);
  else if (idx < 9216)   wprep_one(Wl2, Wtl2, 64, idx - 8192);
}

// ---------------- MFMA GEMM: C[N,TN] = A[N,128] @ W[128,TN] ----------------
// ABF16: A is packed bf16 [N][128 ushorts]; else fp32. OBF16: C bf16 else fp32.
template <int TN, bool RELU, bool HASBIAS, bool ABF16, bool OBF16>
__global__ __launch_bounds__(256) void mfma_gemm_kernel(const void* __restrict__ Av,
                                                        const ushort* __restrict__ Wt,
                                                        const float* __restrict__ bias,
                                                        void* __restrict__ Cv, int n) {
  constexpr int WCOLS = TN / 2;
  constexpr int FI = 4;
  constexpr int FJ = WCOLS / 16;
  __shared__ char lds[32768 + TN * 256];
  ushort* sA = (ushort*)lds;
  ushort* sW = (ushort*)(lds + 32768);

  const int t = threadIdx.x;
  const int row0 = blockIdx.x * 128;
  const int lane = t & 63;
  const int wid = t >> 6;
  const int wr = wid >> 1, wc = wid & 1;

  #pragma unroll
  for (int i = 0; i < 8; ++i) {
    int r = i * 16 + (t >> 4);
    int c = t & 15;
    int gr = row0 + r;
    ushort8 o = 0;
    if (ABF16) {
      const ushort* Ab = (const ushort*)Av;
      if (gr < n) o = *(const ushort8*)(Ab + (size_t)gr * 128 + c * 8);
    } else {
      const float* A = (const float*)Av;
      float4 v0 = make_float4(0.f, 0.f, 0.f, 0.f), v1 = v0;
      if (gr < n) {
        const float4* Ar = (const float4*)(A + (size_t)gr * 128);
        v0 = Ar[c * 2];
        v1 = Ar[c * 2 + 1];
      }
      o[0] = f2bf_rne(v0.x); o[1] = f2bf_rne(v0.y); o[2] = f2bf_rne(v0.z); o[3] = f2bf_rne(v0.w);
      o[4] = f2bf_rne(v1.x); o[5] = f2bf_rne(v1.y); o[6] = f2bf_rne(v1.z); o[7] = f2bf_rne(v1.w);
    }
    *(ushort8*)(sA + r * 128 + ((c ^ (r & 7)) * 8)) = o;
  }
  #pragma unroll
  for (int i = 0; i < TN / 16; ++i) {
    int chunk = i * 256 + t;
    *(ushort8*)(sW + chunk * 8) = *(const ushort8*)(Wt + chunk * 8);
  }
  __syncthreads();

  f32x4 acc[FI][FJ] = {};
  const int lm = lane & 15, q = lane >> 4, l7 = lane & 7;

  #pragma unroll
  for (int kk = 0; kk < 4; ++kk) {
    const int cs = kk * 4 + q;
    short8 af[FI], bfr[FJ];
    #pragma unroll
    for (int i = 0; i < FI; ++i) {
      int r = wr * 64 + i * 16 + lm;
      af[i] = *(const short8*)(sA + r * 128 + ((cs ^ l7) * 8));
    }
    #pragma unroll
    for (int j = 0; j < FJ; ++j) {
      int nn = wc * WCOLS + j * 16 + lm;
      bfr[j] = *(const short8*)(sW + nn * 128 + ((cs ^ l7) * 8));
    }
    #pragma unroll
    for (int i = 0; i < FI; ++i)
      #pragma unroll
      for (int j = 0; j < FJ; ++j)
        acc[i][j] = __builtin_amdgcn_mfma_f32_16x16x32_bf16(af[i], bfr[j], acc[i][j], 0, 0, 0);
  }

  #pragma unroll
  for (int i = 0; i < FI; ++i) {
    #pragma unroll
    for (int j = 0; j < FJ; ++j) {
      int gcol = wc * WCOLS + j * 16 + lm;
      float bv = HASBIAS ? bias[gcol] : 0.f;
      #pragma unroll
      for (int r = 0; r < 4; ++r) {
        int grow = row0 + wr * 64 + i * 16 + q * 4 + r;
        if (grow < n) {
          float v = acc[i][j][r] + bv;
          if (RELU) v = fmaxf(v, 0.f);
          if (OBF16) ((ushort*)Cv)[(size_t)grow * TN + gcol] = f2bf_rne(v);
          else       ((float*)Cv)[(size_t)grow * TN + gcol] = v;
        }
      }
    }
  }
}

// ---------------- vs/vd = W @ a (layer 1 dst path) ----------------
__global__ void make_v2_kernel(const float* __restrict__ Ws, const float* __restrict__ as_,
                               const float* __restrict__ Wd, const float* __restrict__ ad_,
                               float* __restrict__ vs, float* __restrict__ vd) {
  int gw = blockIdx.x * (blockDim.x >> 6) + (threadIdx.x >> 6);
  int lane = threadIdx.x & 63;
  int d = gw & 127;
  const float* W = (gw < 128) ? Ws : Wd;
  const float* a = (gw < 128) ? as_ : ad_;
  float2 w0 = ((const float2*)(W + d * 128))[lane];
  float2 a0 = ((const float2*)a)[lane];
  float p = w0.x * a0.x + w0.y * a0.y;
  #pragma unroll
  for (int off = 32; off >= 1; off >>= 1) p += __shfl_down(p, off, 64);
  if (lane == 0) ((gw < 128) ? vs : vd)[d] = p;
}

// ---------------- alpha from fp32 X (layer 1) ----------------
__global__ void alpha_kernel(const float* __restrict__ X, const float* __restrict__ vs,
                             const float* __restrict__ vd, float* __restrict__ as_,
                             float* __restrict__ ad_, int n) {
  int wid = blockIdx.x * (blockDim.x >> 6) + (threadIdx.x >> 6);
  int lane = threadIdx.x & 63;
  if (wid >= n) return;
  float2 xv = ((const float2*)X)[(size_t)wid * 64 + lane];
  float2 v1 = ((const float2*)vs)[lane];
  float2 v2 = ((const float2*)vd)[lane];
  float ps = xv.x * v1.x + xv.y * v1.y;
  float pd = xv.x * v2.x + xv.y * v2.y;
  #pragma unroll
  for (int off = 32; off > 0; off >>= 1) {
    ps += __shfl_down(ps, off, 64);
    pd += __shfl_down(pd, off, 64);
  }
  if (lane == 0) { as_[wid] = ps; ad_[wid] = pd; }
}

// ---------------- alpha from row-major bf16 hs (layers 2,3) ----------------
__global__ void alphaQ_kernel(const uint* __restrict__ hsb, const float* __restrict__ a_s,
                              const float* __restrict__ a_d, float* __restrict__ as_,
                              float* __restrict__ ad_, int n) {
  int wid = blockIdx.x * (blockDim.x >> 6) + (threadIdx.x >> 6);
  int lane = threadIdx.x & 63;
  if (wid >= n) return;
  uint h = hsb[(size_t)wid * 64 + lane];
  float hx = __uint_as_float(h << 16), hy = __uint_as_float(h & 0xFFFF0000u);
  float2 s2 = ((const float2*)a_s)[lane];
  float2 d2 = ((const float2*)a_d)[lane];
  float ps = hx * s2.x + hy * s2.y;
  float pd = hx * d2.x + hy * d2.y;
  #pragma unroll
  for (int off = 32; off > 0; off >>= 1) {
    ps += __shfl_down(ps, off, 64);
    pd += __shfl_down(pd, off, 64);
  }
  if (lane == 0) { as_[wid] = ps; ad_[wid] = pd; }
}

// ---------------- per-edge records: erec[j] = (src, exp(lrelu(as+ad))) ----------------
__global__ void edge_p_kernel(const int* __restrict__ row_ptr, const int* __restrict__ src_sorted,
                              const float* __restrict__ alpha_s, const float* __restrict__ alpha_d,
                              uint2* __restrict__ erec, int n) {
  int wid = blockIdx.x * (blockDim.x >> 6) + (threadIdx.x >> 6);
  int lane = threadIdx.x & 63;
  int node = wid * 4 + (lane >> 4);
  if (node >= n) return;
  int beg = row_ptr[node], end = row_ptr[node + 1];
  float ad = alpha_d[node];
  for (int j = beg + (lane & 15); j < end; j += 16) {
    int u = src_sorted[j];
    float e = alpha_s[u] + ad;
    e = (e > 0.f) ? e : 0.2f * e;
    erec[j] = make_uint2((uint)u, __float_as_uint(__expf(e)));
  }
}

// ---------------- GAT aggregation: one wave per node, 8 edges in flight ----------
// Output bf16-packed (uint = 2 bf16): numerically identical to fp32 store +
// bf16 round at the consumer's staging.
__global__ void gat_aggregate_kernel(const uint* __restrict__ hsb,
                                     const uint2* __restrict__ erec,
                                     const int* __restrict__ row_ptr,
                                     const float* __restrict__ bias,
                                     uint* __restrict__ outb, int n) {
  int wid = blockIdx.x * (blockDim.x >> 6) + (threadIdx.x >> 6);
  int lane = threadIdx.x & 63;
  if (wid >= n) return;
  int beg = row_ptr[wid], end = row_ptr[wid + 1];
  float s0 = 0.f, s1 = 0.f, s2 = 0.f, s3 = 0.f;
  float a0x = 0.f, a0y = 0.f, a1x = 0.f, a1y = 0.f;
  float a2x = 0.f, a2y = 0.f, a3x = 0.f, a3y = 0.f;
  int j = beg;
  for (; j + 8 <= end; j += 8) {
    uint4 e01 = *(const uint4*)&erec[j + 0];
    uint4 e23 = *(const uint4*)&erec[j + 2];
    uint4 e45 = *(const uint4*)&erec[j + 4];
    uint4 e67 = *(const uint4*)&erec[j + 6];
    uint h0 = hsb[(size_t)e01.x * 64 + lane];
    uint h1 = hsb[(size_t)e01.z * 64 + lane];
    uint h2 = hsb[(size_t)e23.x * 64 + lane];
    uint h3 = hsb[(size_t)e23.z * 64 + lane];
    uint h4 = hsb[(size_t)e45.x * 64 + lane];
    uint h5 = hsb[(size_t)e45.z * 64 + lane];
    uint h6 = hsb[(size_t)e67.x * 64 + lane];
    uint h7 = hsb[(size_t)e67.z * 64 + lane];
    float p0 = __uint_as_float(e01.y), p1 = __uint_as_float(e01.w);
    float p2 = __uint_as_float(e23.y), p3 = __uint_as_float(e23.w);
    float p4 = __uint_as_float(e45.y), p5 = __uint_as_float(e45.w);
    float p6 = __uint_as_float(e67.y), p7 = __uint_as_float(e67.w);
    s0 += p0; a0x = fmaf(p0, __uint_as_float(h0 << 16), a0x); a0y = fmaf(p0, __uint_as_float(h0 & 0xFFFF0000u), a0y);
    s1 += p1; a1x = fmaf(p1, __uint_as_float(h1 << 16), a1x); a1y = fmaf(p1, __uint_as_float(h1 & 0xFFFF0000u), a1y);
    s2 += p2; a2x = fmaf(p2, __uint_as_float(h2 << 16), a2x); a2y = fmaf(p2, __uint_as_float(h2 & 0xFFFF0000u), a2y);
    s3 += p3; a3x = fmaf(p3, __uint_as_float(h3 << 16), a3x); a3y = fmaf(p3, __uint_as_float(h3 & 0xFFFF0000u), a3y);
    s0 += p4; a0x = fmaf(p4, __uint_as_float(h4 << 16), a0x); a0y = fmaf(p4, __uint_as_float(h4 & 0xFFFF0000u), a0y);
    s1 += p5; a1x = fmaf(p5, __uint_as_float(h5 << 16), a1x); a1y = fmaf(p5, __uint_as_float(h5 & 0xFFFF0000u), a1y);
    s2 += p6; a2x = fmaf(p6, __uint_as_float(h6 << 16), a2x); a2y = fmaf(p6, __uint_as_float(h6 & 0xFFFF0000u), a2y);
    s3 += p7; a3x = fmaf(p7, __uint_as_float(h7 << 16), a3x); a3y = fmaf(p7, __uint_as_float(h7 & 0xFFFF0000u), a3y);
  }
  for (; j + 4 <= end; j += 4) {
    uint4 e01 = *(const uint4*)&erec[j + 0];
    uint4 e23 = *(const uint4*)&erec[j + 2];
    uint h0 = hsb[(size_t)e01.x * 64 + lane];
    uint h1 = hsb[(size_t)e01.z * 64 + lane];
    uint h2 = hsb[(size_t)e23.x * 64 + lane];
    uint h3 = hsb[(size_t)e23.z * 64 + lane];
    float p0 = __uint_as_float(e01.y), p1 = __uint_as_float(e01.w);
    float p2 = __uint_as_float(e23.y), p3 = __uint_as_float(e23.w);
    s0 += p0; a0x = fmaf(p0, __uint_as_float(h0 << 16), a0x); a0y = fmaf(p0, __uint_as_float(h0 & 0xFFFF0000u), a0y);
    s1 += p1; a1x = fmaf(p1, __uint_as_float(h1 << 16), a1x); a1y = fmaf(p1, __uint_as_float(h1 & 0xFFFF0000u), a1y);
    s2 += p2; a2x = fmaf(p2, __uint_as_float(h2 << 16), a2x); a2y = fmaf(p2, __uint_as_float(h2 & 0xFFFF0000u), a2y);
    s3 += p3; a3x = fmaf(p3, __uint_as_float(h3 << 16), a3x); a3y = fmaf(p3, __uint_as_float(h3 & 0xFFFF0000u), a3y);
  }
  for (; j < end; ++j) {
    uint2 r0 = erec[j];
    float p0 = __uint_as_float(r0.y);
    uint h0 = hsb[(size_t)r0.x * 64 + lane];
    s0 += p0; a0x = fmaf(p0, __uint_as_float(h0 << 16), a0x); a0y = fmaf(p0, __uint_as_float(h0 & 0xFFFF0000u), a0y);
  }
  float s = (s0 + s1) + (s2 + s3);
  float ax = (a0x + a1x) + (a2x + a3x);
  float ay = (a0y + a1y) + (a2y + a3y);
  float inv = 1.f / (s + 1e-16f);
  float2 b = ((const float2*)bias)[lane];
  float o0 = fmaxf(fmaf(ax, inv, b.x), 0.f);
  float o1 = fmaxf(fmaf(ay, inv, b.y), 0.f);
  uint packed = ((uint)f2bf_rne(o1) << 16) | (uint)f2bf_rne(o0);
  outb[(size_t)wid * 64 + lane] = packed;
}

// ---------------------------------------------------------------------------
extern "C" void kernel_launch(void* const* d_in, const int* in_sizes, int n_in,
                              void* d_out, int out_size, void* d_ws, size_t ws_size,
                              hipStream_t stream) {
  const float* x     = (const float*)d_in[0];
  const int*   eidx  = (const int*)d_in[1];
  const float* W1s   = (const float*)d_in[2];
  const float* W1d   = (const float*)d_in[3];
  const float* a1s   = (const float*)d_in[4];
  const float* a1d   = (const float*)d_in[5];
  const float* b1    = (const float*)d_in[6];
  const float* W2    = (const float*)d_in[7];
  const float* a2s   = (const float*)d_in[8];
  const float* a2d   = (const float*)d_in[9];
  const float* b2    = (const float*)d_in[10];
  const float* W3    = (const float*)d_in[11];
  const float* a3s   = (const float*)d_in[12];
  const float* a3d   = (const float*)d_in[13];
  const float* b3    = (const float*)d_in[14];
  const float* Wl1   = (const float*)d_in[15];
  const float* bl1   = (const float*)d_in[16];
  const float* Wl2   = (const float*)d_in[17];
  const float* bl2   = (const float*)d_in[18];
  float* out = (float*)d_out;

  const int N = in_sizes[0] / 128;
  const int E = in_sizes[1] / 2;
  const int* src = eidx;
  const int* dst = eidx + E;
  const int NB = (N + 511) >> 9;

  // ---- workspace layout ----
  char* base = (char*)d_ws;
  size_t off = 0;
  auto alloc = [&](size_t bytes) -> void* {
    void* p = base + off;
    off += (bytes + 511) & ~(size_t)511;
    return p;
  };
  uint*  Pb       = (uint*)alloc((size_t)N * 128 * 2);   // layer io, packed bf16
  uint*  Qb       = (uint*)alloc((size_t)N * 128 * 2);   // messages, packed bf16
  char*  Q2reg    = (char*)alloc((size_t)N * 128 * 4);   // buckets/erec/Q2b region
  uint*  buckets  = (uint*)Q2reg;                        // dead before head
  uint2* erec     = (uint2*)(Q2reg + ((size_t)24 << 20));// dead before head
  ushort* Q2b     = (ushort*)Q2reg;                      // head hidden, bf16 (after erec dead)
  float* alpha_s  = (float*)alloc((size_t)N * 4);
  float* alpha_d  = (float*)alloc((size_t)N * 4);
  float* vs       = (float*)alloc(128 * 4);
  float* vd       = (float*)alloc(128 * 4);
  int* row_ptr    = (int*)alloc((size_t)(N + 1) * 4);
  int* bcount     = (int*)alloc(256 * 4);
  int* bbase      = (int*)alloc(256 * 4);
  int* src_sorted = (int*)alloc((size_t)E * 4);
  ushort* Wt1     = (ushort*)alloc(128 * 128 * 2);
  ushort* Wt2     = (ushort*)alloc(128 * 128 * 2);
  ushort* Wt3     = (ushort*)alloc(128 * 128 * 2);
  ushort* Wtl1    = (ushort*)alloc(128 * 128 * 2);
  ushort* Wtl2    = (ushort*)alloc(64 * 128 * 2);
  (void)ws_size;

  const int TB = 256;
  const int nwaveblk = (N + 3) / 4;
  const int ggrid = (N + 127) / 128;
  const int pagrid = (E + PA_CHUNK - 1) / PA_CHUNK;
  const int epgrid = (N + 15) / 16;

  // ---- CSR build ----
  hipMemsetAsync(bcount, 0, 256 * 4, stream);
  bucket_scatter_kernel<<<pagrid, 256, 0, stream>>>(src, dst, bcount, buckets, E, NB);
  scan_buckets_kernel<<<1, 256, 0, stream>>>(bcount, bbase, NB, row_ptr, N, E);
  bucket_sort_kernel<<<NB, 256, 0, stream>>>(buckets, bcount, bbase, row_ptr, src_sorted, N);

  // ---- weight prep (one launch) ----
  wprep_all_kernel<<<36, 256, 0, stream>>>(W1s, W2, W3, Wl1, Wl2,
                                           Wt1, Wt2, Wt3, Wtl1, Wtl2);

  // ---- layer 1: x -> Pb ----
  make_v2_kernel<<<64, 256, 0, stream>>>(W1s, a1s, W1d, a1d, vs, vd);
  alpha_kernel<<<nwaveblk, TB, 0, stream>>>(x, vs, vd, alpha_s, alpha_d, N);
  mfma_gemm_kernel<128, false, false, false, true><<<ggrid, 256, 0, stream>>>(x, Wt1, nullptr, Qb, N);
  edge_p_kernel<<<epgrid, TB, 0, stream>>>(row_ptr, src_sorted, alpha_s, alpha_d, erec, N);
  gat_aggregate_kernel<<<nwaveblk, TB, 0, stream>>>(Qb, erec, row_ptr, b1, Pb, N);

  // ---- layer 2: Pb -> Pb ----
  mfma_gemm_kernel<128, false, false, true, true><<<ggrid, 256, 0, stream>>>(Pb, Wt2, nullptr, Qb, N);
  alphaQ_kernel<<<nwaveblk, TB, 0, stream>>>(Qb, a2s, a2d, alpha_s, alpha_d, N);
  edge_p_kernel<<<epgrid, TB, 0, stream>>>(row_ptr, src_sorted, alpha_s, alpha_d, erec, N);
  gat_aggregate_kernel<<<nwaveblk, TB, 0, stream>>>(Qb, erec, row_ptr, b2, Pb, N);

  // ---- layer 3: Pb -> Pb ----
  mfma_gemm_kernel<128, false, false, true, true><<<ggrid, 256, 0, stream>>>(Pb, Wt3, nullptr, Qb, N);
  alphaQ_kernel<<<nwaveblk, TB, 0, stream>>>(Qb, a3s, a3d, alpha_s, alpha_d, N);
  edge_p_kernel<<<epgrid, TB, 0, stream>>>(row_ptr, src_sorted, alpha_s, alpha_d, erec, N);
  gat_aggregate_kernel<<<nwaveblk, TB, 0, stream>>>(Qb, erec, row_ptr, b3, Pb, N);

  // ---- MLP head (buckets/erec dead; Q2b reuses the region) ----
  mfma_gemm_kernel<128, true, true, true, true><<<ggrid, 256, 0, stream>>>(Pb, Wtl1, bl1, Q2b, N);
  mfma_gemm_kernel<64, false, true, true, false><<<ggrid, 256, 0, stream>>>(Q2b, Wtl2, bl2, out, N);
}

// Round 11
// 412.643 us; speedup vs baseline: 1.4642x; 1.0214x over previous
//
#include <hip/hip_runtime.h>
#include <hip/hip_bf16.h>
#include <cstdint>
#include <cstddef>

// ---------------------------------------------------------------------------
// GAT x3 + MLP head.
// GEMMs: MFMA bf16 (fp32 accum), 128xTN tile, XOR-swizzled LDS.
// All inter-kernel tensors bf16. Aggregation: CSR-by-dst, 2 NODES PER WAVE
// (32 lanes x 8B per edge row), 8 edges in flight/wave, no cross-lane reduce.
// CSR build = 2-level bucket sort.
// ---------------------------------------------------------------------------

#define PA_CHUNK 4096
#define BKT_CAP  12288

using short8  = __attribute__((ext_vector_type(8))) short;
using ushort8 = __attribute__((ext_vector_type(8))) unsigned short;
using f32x4   = __attribute__((ext_vector_type(4))) float;

__device__ __forceinline__ ushort f2bf_rne(float f) {
  uint u = __float_as_uint(f);
  u += 0x7FFFu + ((u >> 16) & 1u);
  return (ushort)(u >> 16);
}

// ---------------- Phase A: scatter edges into coarse buckets ----------------
__global__ __launch_bounds__(256) void bucket_scatter_kernel(
    const int* __restrict__ src, const int* __restrict__ dst,
    int* __restrict__ bcount, uint* __restrict__ buckets, int E, int NB) {
  __shared__ int  hist[256];
  __shared__ int  base[256];
  __shared__ uint recs[PA_CHUNK];
  __shared__ ushort rb[PA_CHUNK];
  const int t = threadIdx.x;
  const int e0 = blockIdx.x * PA_CHUNK;
  const int nE = min(PA_CHUNK, E - e0);

  for (int i = t; i < 256; i += 256) hist[i] = 0;
  __syncthreads();
  for (int i = t; i < nE; i += 256) {
    int s = src[e0 + i], d = dst[e0 + i];
    int b = d >> 9;
    recs[i] = ((uint)s << 9) | (uint)(d & 511);
    rb[i] = (ushort)b;
    atomicAdd(&hist[b], 1);
  }
  __syncthreads();
  if (t < NB) base[t] = (hist[t] > 0) ? atomicAdd(&bcount[t], hist[t]) : 0;
  __syncthreads();
  for (int i = t; i < 256; i += 256) hist[i] = 0;
  __syncthreads();
  for (int i = t; i < nE; i += 256) {
    int b = rb[i];
    int r = atomicAdd(&hist[b], 1);
    int pos = base[b] + r;
    if (pos < BKT_CAP) buckets[(size_t)b * BKT_CAP + pos] = recs[i];
  }
}

__global__ __launch_bounds__(256) void scan_buckets_kernel(
    const int* __restrict__ bcount, int* __restrict__ bbase, int NB,
    int* __restrict__ row_ptr, int N, int E) {
  __shared__ int s[256];
  int t = threadIdx.x;
  int x = (t < NB) ? bcount[t] : 0;
  s[t] = x;
  __syncthreads();
  #pragma unroll
  for (int off = 1; off < 256; off <<= 1) {
    int v = (t >= off) ? s[t - off] : 0;
    __syncthreads();
    s[t] += v;
    __syncthreads();
  }
  if (t < NB) bbase[t] = s[t] - x;
  if (t == 0) row_ptr[N] = E;
}

__global__ __launch_bounds__(256) void bucket_sort_kernel(
    const uint* __restrict__ buckets, const int* __restrict__ bcount,
    const int* __restrict__ bbase, int* __restrict__ row_ptr,
    int* __restrict__ src_sorted, int N) {
  const int b = blockIdx.x;
  const int t = threadIdx.x;
  __shared__ int h[512], o[512], c[512];
  __shared__ int wsum[4];
  const int cnt = min(bcount[b], BKT_CAP);
  const int gbase = bbase[b];
  const uint* rec = buckets + (size_t)b * BKT_CAP;

  for (int i = t; i < 512; i += 256) { h[i] = 0; c[i] = 0; }
  __syncthreads();
  for (int i = t; i < cnt; i += 256) atomicAdd(&h[rec[i] & 511], 1);
  __syncthreads();

  int a0 = h[2 * t], a1 = h[2 * t + 1];
  int s2 = a0 + a1;
  int lane = t & 63, w = t >> 6;
  int v = s2;
  #pragma unroll
  for (int off = 1; off < 64; off <<= 1) {
    int u = __shfl_up(v, off, 64);
    if (lane >= off) v += u;
  }
  if (lane == 63) wsum[w] = v;
  __syncthreads();
  int woff = 0;
  for (int i = 0; i < w; ++i) woff += wsum[i];
  int excl = (v - s2) + woff;
  o[2 * t]     = excl;
  o[2 * t + 1] = excl + a0;
  __syncthreads();

  for (int i = t; i < 512; i += 256) {
    int node = (b << 9) + i;
    if (node < N) row_ptr[node] = gbase + o[i];
  }
  for (int i = t; i < cnt; i += 256) {
    uint r = rec[i];
    int d9 = r & 511;
    int rk = atomicAdd(&c[d9], 1);
    src_sorted[gbase + o[d9] + rk] = (int)(r >> 9);
  }
}

// ---------------- weight prep (all 5 weights, one launch) ----------------
__device__ __forceinline__ void wprep_one(const float* __restrict__ W,
                                          ushort* __restrict__ Wt, int TN, int local) {
  int n = local % TN;
  int c = local / TN;
  ushort8 o;
  #pragma unroll
  for (int j = 0; j < 8; ++j) o[j] = f2bf_rne(W[(c * 8 + j) * TN + n]);
  *(ushort8*)(Wt + n * 128 + ((c ^ (n & 7)) * 8)) = o;
}

__global__ __launch_bounds__(256) void wprep_all_kernel(
    const float* __restrict__ W1s, const float* __restrict__ W2,
    const float* __restrict__ W3,  const float* __restrict__ Wl1,
    const float* __restrict__ Wl2,
    ushort* __restrict__ Wt1, ushort* __restrict__ Wt2, ushort* __restrict__ Wt3,
    ushort* __restrict__ Wtl1, ushort* __restrict__ Wtl2) {
  int idx = blockIdx.x * 256 + threadIdx.x;   // 0..9215
  if (idx < 2048)        wprep_one(W1s, Wt1, 128, idx);
  else if (idx < 4096)   wprep_one(W2,  Wt2, 128, idx - 2048);
  else if (idx < 6144)   wprep_one(W3,  Wt3, 128, idx - 4096);
  else if (idx < 8192)   wprep_one(Wl1, Wtl1, 128, idx - 6144);
  else if (idx < 9216)   wprep_one(Wl2, Wtl2, 64, idx - 8192);
}

// ---------------- MFMA GEMM: C[N,TN] = A[N,128] @ W[128,TN] ----------------
template <int TN, bool RELU, bool HASBIAS, bool ABF16, bool OBF16>
__global__ __launch_bounds__(256) void mfma_gemm_kernel(const void* __restrict__ Av,
                                                        const ushort* __restrict__ Wt,
                                                        const float* __restrict__ bias,
                                                        void* __restrict__ Cv, int n) {
  constexpr int WCOLS = TN / 2;
  constexpr int FI = 4;
  constexpr int FJ = WCOLS / 16;
  __shared__ char lds[32768 + TN * 256];
  ushort* sA = (ushort*)lds;
  ushort* sW = (ushort*)(lds + 32768);

  const int t = threadIdx.x;
  const int row0 = blockIdx.x * 128;
  const int lane = t & 63;
  const int wid = t >> 6;
  const int wr = wid >> 1, wc = wid & 1;

  #pragma unroll
  for (int i = 0; i < 8; ++i) {
    int r = i * 16 + (t >> 4);
    int c = t & 15;
    int gr = row0 + r;
    ushort8 o = 0;
    if (ABF16) {
      const ushort* Ab = (const ushort*)Av;
      if (gr < n) o = *(const ushort8*)(Ab + (size_t)gr * 128 + c * 8);
    } else {
      const float* A = (const float*)Av;
      float4 v0 = make_float4(0.f, 0.f, 0.f, 0.f), v1 = v0;
      if (gr < n) {
        const float4* Ar = (const float4*)(A + (size_t)gr * 128);
        v0 = Ar[c * 2];
        v1 = Ar[c * 2 + 1];
      }
      o[0] = f2bf_rne(v0.x); o[1] = f2bf_rne(v0.y); o[2] = f2bf_rne(v0.z); o[3] = f2bf_rne(v0.w);
      o[4] = f2bf_rne(v1.x); o[5] = f2bf_rne(v1.y); o[6] = f2bf_rne(v1.z); o[7] = f2bf_rne(v1.w);
    }
    *(ushort8*)(sA + r * 128 + ((c ^ (r & 7)) * 8)) = o;
  }
  #pragma unroll
  for (int i = 0; i < TN / 16; ++i) {
    int chunk = i * 256 + t;
    *(ushort8*)(sW + chunk * 8) = *(const ushort8*)(Wt + chunk * 8);
  }
  __syncthreads();

  f32x4 acc[FI][FJ] = {};
  const int lm = lane & 15, q = lane >> 4, l7 = lane & 7;

  #pragma unroll
  for (int kk = 0; kk < 4; ++kk) {
    const int cs = kk * 4 + q;
    short8 af[FI], bfr[FJ];
    #pragma unroll
    for (int i = 0; i < FI; ++i) {
      int r = wr * 64 + i * 16 + lm;
      af[i] = *(const short8*)(sA + r * 128 + ((cs ^ l7) * 8));
    }
    #pragma unroll
    for (int j = 0; j < FJ; ++j) {
      int nn = wc * WCOLS + j * 16 + lm;
      bfr[j] = *(const short8*)(sW + nn * 128 + ((cs ^ l7) * 8));
    }
    #pragma unroll
    for (int i = 0; i < FI; ++i)
      #pragma unroll
      for (int j = 0; j < FJ; ++j)
        acc[i][j] = __builtin_amdgcn_mfma_f32_16x16x32_bf16(af[i], bfr[j], acc[i][j], 0, 0, 0);
  }

  #pragma unroll
  for (int i = 0; i < FI; ++i) {
    #pragma unroll
    for (int j = 0; j < FJ; ++j) {
      int gcol = wc * WCOLS + j * 16 + lm;
      float bv = HASBIAS ? bias[gcol] : 0.f;
      #pragma unroll
      for (int r = 0; r < 4; ++r) {
        int grow = row0 + wr * 64 + i * 16 + q * 4 + r;
        if (grow < n) {
          float v = acc[i][j][r] + bv;
          if (RELU) v = fmaxf(v, 0.f);
          if (OBF16) ((ushort*)Cv)[(size_t)grow * TN + gcol] = f2bf_rne(v);
          else       ((float*)Cv)[(size_t)grow * TN + gcol] = v;
        }
      }
    }
  }
}

// ---------------- vs/vd = W @ a (layer 1 dst path) ----------------
__global__ void make_v2_kernel(const float* __restrict__ Ws, const float* __restrict__ as_,
                               const float* __restrict__ Wd, const float* __restrict__ ad_,
                               float* __restrict__ vs, float* __restrict__ vd) {
  int gw = blockIdx.x * (blockDim.x >> 6) + (threadIdx.x >> 6);
  int lane = threadIdx.x & 63;
  int d = gw & 127;
  const float* W = (gw < 128) ? Ws : Wd;
  const float* a = (gw < 128) ? as_ : ad_;
  float2 w0 = ((const float2*)(W + d * 128))[lane];
  float2 a0 = ((const float2*)a)[lane];
  float p = w0.x * a0.x + w0.y * a0.y;
  #pragma unroll
  for (int off = 32; off >= 1; off >>= 1) p += __shfl_down(p, off, 64);
  if (lane == 0) ((gw < 128) ? vs : vd)[d] = p;
}

// ---------------- alpha from fp32 X (layer 1) ----------------
__global__ void alpha_kernel(const float* __restrict__ X, const float* __restrict__ vs,
                             const float* __restrict__ vd, float* __restrict__ as_,
                             float* __restrict__ ad_, int n) {
  int wid = blockIdx.x * (blockDim.x >> 6) + (threadIdx.x >> 6);
  int lane = threadIdx.x & 63;
  if (wid >= n) return;
  float2 xv = ((const float2*)X)[(size_t)wid * 64 + lane];
  float2 v1 = ((const float2*)vs)[lane];
  float2 v2 = ((const float2*)vd)[lane];
  float ps = xv.x * v1.x + xv.y * v1.y;
  float pd = xv.x * v2.x + xv.y * v2.y;
  #pragma unroll
  for (int off = 32; off > 0; off >>= 1) {
    ps += __shfl_down(ps, off, 64);
    pd += __shfl_down(pd, off, 64);
  }
  if (lane == 0) { as_[wid] = ps; ad_[wid] = pd; }
}

// ---------------- alpha from row-major bf16 hs (layers 2,3) ----------------
__global__ void alphaQ_kernel(const uint* __restrict__ hsb, const float* __restrict__ a_s,
                              const float* __restrict__ a_d, float* __restrict__ as_,
                              float* __restrict__ ad_, int n) {
  int wid = blockIdx.x * (blockDim.x >> 6) + (threadIdx.x >> 6);
  int lane = threadIdx.x & 63;
  if (wid >= n) return;
  uint h = hsb[(size_t)wid * 64 + lane];
  float hx = __uint_as_float(h << 16), hy = __uint_as_float(h & 0xFFFF0000u);
  float2 s2 = ((const float2*)a_s)[lane];
  float2 d2 = ((const float2*)a_d)[lane];
  float ps = hx * s2.x + hy * s2.y;
  float pd = hx * d2.x + hy * d2.y;
  #pragma unroll
  for (int off = 32; off > 0; off >>= 1) {
    ps += __shfl_down(ps, off, 64);
    pd += __shfl_down(pd, off, 64);
  }
  if (lane == 0) { as_[wid] = ps; ad_[wid] = pd; }
}

// ---------------- per-edge records: erec[j] = (src, exp(lrelu(as+ad))) ----------------
__global__ void edge_p_kernel(const int* __restrict__ row_ptr, const int* __restrict__ src_sorted,
                              const float* __restrict__ alpha_s, const float* __restrict__ alpha_d,
                              uint2* __restrict__ erec, int n) {
  int wid = blockIdx.x * (blockDim.x >> 6) + (threadIdx.x >> 6);
  int lane = threadIdx.x & 63;
  int node = wid * 4 + (lane >> 4);
  if (node >= n) return;
  int beg = row_ptr[node], end = row_ptr[node + 1];
  float ad = alpha_d[node];
  for (int j = beg + (lane & 15); j < end; j += 16) {
    int u = src_sorted[j];
    float e = alpha_s[u] + ad;
    e = (e > 0.f) ? e : 0.2f * e;
    erec[j] = make_uint2((uint)u, __float_as_uint(__expf(e)));
  }
}

// ---------------- GAT aggregation: 2 nodes per wave, 8B/lane gathers ----------
// Wave = 2 x (32 lanes, one node each). Each lane owns 4 dims (uint2 = 4 bf16).
// Per 8-edge iteration: 4 gather instrs (each serving both halves) + 2 erec
// uint4 loads. Output bf16-packed.
__global__ void gat_aggregate_kernel(const uint2* __restrict__ hs2,
                                     const uint2* __restrict__ erec,
                                     const int* __restrict__ row_ptr,
                                     const float* __restrict__ bias,
                                     uint2* __restrict__ outb, int n) {
  const int t = threadIdx.x;
  const int pairw = blockIdx.x * 4 + (t >> 6);   // wave index
  const int lane = t & 63;
  const int half = lane >> 5;
  const int sl = lane & 31;
  const int node = pairw * 2 + half;
  const bool active = node < n;
  const int beg = active ? row_ptr[node] : 0;
  const int end = active ? row_ptr[node + 1] : 0;

  float sA = 0.f, sB = 0.f;
  // dim accumulators: lane owns dims 4*sl..4*sl+3 -> (x0,y0) from uint0, (x1,y1) from uint1
  float Ax0 = 0.f, Ay0 = 0.f, Ax1 = 0.f, Ay1 = 0.f;   // chain A (edges 0,1)
  float Bx0 = 0.f, By0 = 0.f, Bx1 = 0.f, By1 = 0.f;   // chain B (edges 2,3)

  int j = beg;
  for (; j + 4 <= end; j += 4) {
    uint4 eA = *(const uint4*)&erec[j];       // edges j, j+1 (16B, uniform per half)
    uint4 eB = *(const uint4*)&erec[j + 2];   // edges j+2, j+3
    uint2 h0 = hs2[(size_t)eA.x * 32 + sl];
    uint2 h1 = hs2[(size_t)eA.z * 32 + sl];
    uint2 h2 = hs2[(size_t)eB.x * 32 + sl];
    uint2 h3 = hs2[(size_t)eB.z * 32 + sl];
    float p0 = __uint_as_float(eA.y), p1 = __uint_as_float(eA.w);
    float p2 = __uint_as_float(eB.y), p3 = __uint_as_float(eB.w);
    sA += p0 + p1;
    sB += p2 + p3;
    Ax0 = fmaf(p0, __uint_as_float(h0.x << 16), Ax0);
    Ay0 = fmaf(p0, __uint_as_float(h0.x & 0xFFFF0000u), Ay0);
    Ax1 = fmaf(p0, __uint_as_float(h0.y << 16), Ax1);
    Ay1 = fmaf(p0, __uint_as_float(h0.y & 0xFFFF0000u), Ay1);
    Bx0 = fmaf(p1, __uint_as_float(h1.x << 16), Bx0);
    By0 = fmaf(p1, __uint_as_float(h1.x & 0xFFFF0000u), By0);
    Bx1 = fmaf(p1, __uint_as_float(h1.y << 16), Bx1);
    By1 = fmaf(p1, __uint_as_float(h1.y & 0xFFFF0000u), By1);
    Ax0 = fmaf(p2, __uint_as_float(h2.x << 16), Ax0);
    Ay0 = fmaf(p2, __uint_as_float(h2.x & 0xFFFF0000u), Ay0);
    Ax1 = fmaf(p2, __uint_as_float(h2.y << 16), Ax1);
    Ay1 = fmaf(p2, __uint_as_float(h2.y & 0xFFFF0000u), Ay1);
    Bx0 = fmaf(p3, __uint_as_float(h3.x << 16), Bx0);
    By0 = fmaf(p3, __uint_as_float(h3.x & 0xFFFF0000u), By0);
    Bx1 = fmaf(p3, __uint_as_float(h3.y << 16), Bx1);
    By1 = fmaf(p3, __uint_as_float(h3.y & 0xFFFF0000u), By1);
  }
  for (; j < end; ++j) {
    uint2 r = erec[j];
    float p = __uint_as_float(r.y);
    uint2 h = hs2[(size_t)r.x * 32 + sl];
    sA += p;
    Ax0 = fmaf(p, __uint_as_float(h.x << 16), Ax0);
    Ay0 = fmaf(p, __uint_as_float(h.x & 0xFFFF0000u), Ay0);
    Ax1 = fmaf(p, __uint_as_float(h.y << 16), Ax1);
    Ay1 = fmaf(p, __uint_as_float(h.y & 0xFFFF0000u), Ay1);
  }

  if (active) {
    float s = sA + sB;
    float inv = 1.f / (s + 1e-16f);
    float4 bv = ((const float4*)bias)[sl];
    float o0 = fmaxf(fmaf(Ax0 + Bx0, inv, bv.x), 0.f);
    float o1 = fmaxf(fmaf(Ay0 + By0, inv, bv.y), 0.f);
    float o2 = fmaxf(fmaf(Ax1 + Bx1, inv, bv.z), 0.f);
    float o3 = fmaxf(fmaf(Ay1 + By1, inv, bv.w), 0.f);
    uint2 pk;
    pk.x = ((uint)f2bf_rne(o1) << 16) | (uint)f2bf_rne(o0);
    pk.y = ((uint)f2bf_rne(o3) << 16) | (uint)f2bf_rne(o2);
    outb[(size_t)node * 32 + sl] = pk;
  }
}

// ---------------------------------------------------------------------------
extern "C" void kernel_launch(void* const* d_in, const int* in_sizes, int n_in,
                              void* d_out, int out_size, void* d_ws, size_t ws_size,
                              hipStream_t stream) {
  const float* x     = (const float*)d_in[0];
  const int*   eidx  = (const int*)d_in[1];
  const float* W1s   = (const float*)d_in[2];
  const float* W1d   = (const float*)d_in[3];
  const float* a1s   = (const float*)d_in[4];
  const float* a1d   = (const float*)d_in[5];
  const float* b1    = (const float*)d_in[6];
  const float* W2    = (const float*)d_in[7];
  const float* a2s   = (const float*)d_in[8];
  const float* a2d   = (const float*)d_in[9];
  const float* b2    = (const float*)d_in[10];
  const float* W3    = (const float*)d_in[11];
  const float* a3s   = (const float*)d_in[12];
  const float* a3d   = (const float*)d_in[13];
  const float* b3    = (const float*)d_in[14];
  const float* Wl1   = (const float*)d_in[15];
  const float* bl1   = (const float*)d_in[16];
  const float* Wl2   = (const float*)d_in[17];
  const float* bl2   = (const float*)d_in[18];
  float* out = (float*)d_out;

  const int N = in_sizes[0] / 128;
  const int E = in_sizes[1] / 2;
  const int* src = eidx;
  const int* dst = eidx + E;
  const int NB = (N + 511) >> 9;

  // ---- workspace layout ----
  char* base = (char*)d_ws;
  size_t off = 0;
  auto alloc = [&](size_t bytes) -> void* {
    void* p = base + off;
    off += (bytes + 511) & ~(size_t)511;
    return p;
  };
  uint*  Pb       = (uint*)alloc((size_t)N * 128 * 2);   // layer io, packed bf16
  uint*  Qb       = (uint*)alloc((size_t)N * 128 * 2);   // messages, packed bf16
  char*  Q2reg    = (char*)alloc((size_t)N * 128 * 4);   // buckets/erec/Q2b region
  uint*  buckets  = (uint*)Q2reg;                        // dead before head
  uint2* erec     = (uint2*)(Q2reg + ((size_t)24 << 20));// dead before head
  ushort* Q2b     = (ushort*)Q2reg;                      // head hidden, bf16
  float* alpha_s  = (float*)alloc((size_t)N * 4);
  float* alpha_d  = (float*)alloc((size_t)N * 4);
  float* vs       = (float*)alloc(128 * 4);
  float* vd       = (float*)alloc(128 * 4);
  int* row_ptr    = (int*)alloc((size_t)(N + 1) * 4);
  int* bcount     = (int*)alloc(256 * 4);
  int* bbase      = (int*)alloc(256 * 4);
  int* src_sorted = (int*)alloc((size_t)E * 4);
  ushort* Wt1     = (ushort*)alloc(128 * 128 * 2);
  ushort* Wt2     = (ushort*)alloc(128 * 128 * 2);
  ushort* Wt3     = (ushort*)alloc(128 * 128 * 2);
  ushort* Wtl1    = (ushort*)alloc(128 * 128 * 2);
  ushort* Wtl2    = (ushort*)alloc(64 * 128 * 2);
  (void)ws_size;

  const int TB = 256;
  const int nwaveblk = (N + 3) / 4;
  const int ggrid = (N + 127) / 128;
  const int pagrid = (E + PA_CHUNK - 1) / PA_CHUNK;
  const int epgrid = (N + 15) / 16;
  const int aggrid = (N + 7) / 8;            // 4 waves/block, 2 nodes/wave

  // ---- CSR build ----
  hipMemsetAsync(bcount, 0, 256 * 4, stream);
  bucket_scatter_kernel<<<pagrid, 256, 0, stream>>>(src, dst, bcount, buckets, E, NB);
  scan_buckets_kernel<<<1, 256, 0, stream>>>(bcount, bbase, NB, row_ptr, N, E);
  bucket_sort_kernel<<<NB, 256, 0, stream>>>(buckets, bcount, bbase, row_ptr, src_sorted, N);

  // ---- weight prep (one launch) ----
  wprep_all_kernel<<<36, 256, 0, stream>>>(W1s, W2, W3, Wl1, Wl2,
                                           Wt1, Wt2, Wt3, Wtl1, Wtl2);

  // ---- layer 1: x -> Pb ----
  make_v2_kernel<<<64, 256, 0, stream>>>(W1s, a1s, W1d, a1d, vs, vd);
  alpha_kernel<<<nwaveblk, TB, 0, stream>>>(x, vs, vd, alpha_s, alpha_d, N);
  mfma_gemm_kernel<128, false, false, false, true><<<ggrid, 256, 0, stream>>>(x, Wt1, nullptr, Qb, N);
  edge_p_kernel<<<epgrid, TB, 0, stream>>>(row_ptr, src_sorted, alpha_s, alpha_d, erec, N);
  gat_aggregate_kernel<<<aggrid, TB, 0, stream>>>((const uint2*)Qb, erec, row_ptr, b1, (uint2*)Pb, N);

  // ---- layer 2: Pb -> Pb ----
  mfma_gemm_kernel<128, false, false, true, true><<<ggrid, 256, 0, stream>>>(Pb, Wt2, nullptr, Qb, N);
  alphaQ_kernel<<<nwaveblk, TB, 0, stream>>>(Qb, a2s, a2d, alpha_s, alpha_d, N);
  edge_p_kernel<<<epgrid, TB, 0, stream>>>(row_ptr, src_sorted, alpha_s, alpha_d, erec, N);
  gat_aggregate_kernel<<<aggrid, TB, 0, stream>>>((const uint2*)Qb, erec, row_ptr, b2, (uint2*)Pb, N);

  // ---- layer 3: Pb -> Pb ----
  mfma_gemm_kernel<128, false, false, true, true><<<ggrid, 256, 0, stream>>>(Pb, Wt3, nullptr, Qb, N);
  alphaQ_kernel<<<nwaveblk, TB, 0, stream>>>(Qb, a3s, a3d, alpha_s, alpha_d, N);
  edge_p_kernel<<<epgrid, TB, 0, stream>>>(row_ptr, src_sorted, alpha_s, alpha_d, erec, N);
  gat_aggregate_kernel<<<aggrid, TB, 0, stream>>>((const uint2*)Qb, erec, row_ptr, b3, (uint2*)Pb, N);

  // ---- MLP head (buckets/erec dead; Q2b reuses the region) ----
  mfma_gemm_kernel<128, true, true, true, true><<<ggrid, 256, 0, stream>>>(Pb, Wtl1, bl1, Q2b, N);
  mfma_gemm_kernel<64, false, true, true, false><<<ggrid, 256, 0, stream>>>(Q2b, Wtl2, bl2, out, N);
}

// Round 12
// 385.216 us; speedup vs baseline: 1.5684x; 1.0712x over previous
//
#include <hip/hip_runtime.h>
#include <hip/hip_bf16.h>
#include <cstdint>
#include <cstddef>

// ---------------------------------------------------------------------------
// GAT x3 + MLP head.
// GEMMs: MFMA bf16 (fp32 accum), 128xTN tile, XOR-swizzled LDS, with FUSED
// alpha epilogue (alpha_s/alpha_d dot products from fp32 accumulators; layer-1
// alpha_d = x@vd fused into staging). All inter-kernel tensors bf16.
// Aggregation: CSR-by-dst, 2 nodes/wave, 8 edges in flight.
// CSR build = 2-level bucket sort.
// ---------------------------------------------------------------------------

#define PA_CHUNK 4096
#define BKT_CAP  12288

using short8  = __attribute__((ext_vector_type(8))) short;
using ushort8 = __attribute__((ext_vector_type(8))) unsigned short;
using f32x4   = __attribute__((ext_vector_type(4))) float;

__device__ __forceinline__ ushort f2bf_rne(float f) {
  uint u = __float_as_uint(f);
  u += 0x7FFFu + ((u >> 16) & 1u);
  return (ushort)(u >> 16);
}

// ---------------- Phase A: scatter edges into coarse buckets ----------------
__global__ __launch_bounds__(256) void bucket_scatter_kernel(
    const int* __restrict__ src, const int* __restrict__ dst,
    int* __restrict__ bcount, uint* __restrict__ buckets, int E, int NB) {
  __shared__ int  hist[256];
  __shared__ int  base[256];
  __shared__ uint recs[PA_CHUNK];
  __shared__ ushort rb[PA_CHUNK];
  const int t = threadIdx.x;
  const int e0 = blockIdx.x * PA_CHUNK;
  const int nE = min(PA_CHUNK, E - e0);

  for (int i = t; i < 256; i += 256) hist[i] = 0;
  __syncthreads();
  for (int i = t; i < nE; i += 256) {
    int s = src[e0 + i], d = dst[e0 + i];
    int b = d >> 9;
    recs[i] = ((uint)s << 9) | (uint)(d & 511);
    rb[i] = (ushort)b;
    atomicAdd(&hist[b], 1);
  }
  __syncthreads();
  if (t < NB) base[t] = (hist[t] > 0) ? atomicAdd(&bcount[t], hist[t]) : 0;
  __syncthreads();
  for (int i = t; i < 256; i += 256) hist[i] = 0;
  __syncthreads();
  for (int i = t; i < nE; i += 256) {
    int b = rb[i];
    int r = atomicAdd(&hist[b], 1);
    int pos = base[b] + r;
    if (pos < BKT_CAP) buckets[(size_t)b * BKT_CAP + pos] = recs[i];
  }
}

__global__ __launch_bounds__(256) void scan_buckets_kernel(
    const int* __restrict__ bcount, int* __restrict__ bbase, int NB,
    int* __restrict__ row_ptr, int N, int E) {
  __shared__ int s[256];
  int t = threadIdx.x;
  int x = (t < NB) ? bcount[t] : 0;
  s[t] = x;
  __syncthreads();
  #pragma unroll
  for (int off = 1; off < 256; off <<= 1) {
    int v = (t >= off) ? s[t - off] : 0;
    __syncthreads();
    s[t] += v;
    __syncthreads();
  }
  if (t < NB) bbase[t] = s[t] - x;
  if (t == 0) row_ptr[N] = E;
}

__global__ __launch_bounds__(256) void bucket_sort_kernel(
    const uint* __restrict__ buckets, const int* __restrict__ bcount,
    const int* __restrict__ bbase, int* __restrict__ row_ptr,
    int* __restrict__ src_sorted, int N) {
  const int b = blockIdx.x;
  const int t = threadIdx.x;
  __shared__ int h[512], o[512], c[512];
  __shared__ int wsum[4];
  const int cnt = min(bcount[b], BKT_CAP);
  const int gbase = bbase[b];
  const uint* rec = buckets + (size_t)b * BKT_CAP;

  for (int i = t; i < 512; i += 256) { h[i] = 0; c[i] = 0; }
  __syncthreads();
  for (int i = t; i < cnt; i += 256) atomicAdd(&h[rec[i] & 511], 1);
  __syncthreads();

  int a0 = h[2 * t], a1 = h[2 * t + 1];
  int s2 = a0 + a1;
  int lane = t & 63, w = t >> 6;
  int v = s2;
  #pragma unroll
  for (int off = 1; off < 64; off <<= 1) {
    int u = __shfl_up(v, off, 64);
    if (lane >= off) v += u;
  }
  if (lane == 63) wsum[w] = v;
  __syncthreads();
  int woff = 0;
  for (int i = 0; i < w; ++i) woff += wsum[i];
  int excl = (v - s2) + woff;
  o[2 * t]     = excl;
  o[2 * t + 1] = excl + a0;
  __syncthreads();

  for (int i = t; i < 512; i += 256) {
    int node = (b << 9) + i;
    if (node < N) row_ptr[node] = gbase + o[i];
  }
  for (int i = t; i < cnt; i += 256) {
    uint r = rec[i];
    int d9 = r & 511;
    int rk = atomicAdd(&c[d9], 1);
    src_sorted[gbase + o[d9] + rk] = (int)(r >> 9);
  }
}

// ---------------- weight prep (all 5 weights, one launch) ----------------
__device__ __forceinline__ void wprep_one(const float* __restrict__ W,
                                          ushort* __restrict__ Wt, int TN, int local) {
  int n = local % TN;
  int c = local / TN;
  ushort8 o;
  #pragma unroll
  for (int j = 0; j < 8; ++j) o[j] = f2bf_rne(W[(c * 8 + j) * TN + n]);
  *(ushort8*)(Wt + n * 128 + ((c ^ (n & 7)) * 8)) = o;
}

__global__ __launch_bounds__(256) void wprep_all_kernel(
    const float* __restrict__ W1s, const float* __restrict__ W2,
    const float* __restrict__ W3,  const float* __restrict__ Wl1,
    const float* __restrict__ Wl2,
    ushort* __restrict__ Wt1, ushort* __restrict__ Wt2, ushort* __restrict__ Wt3,
    ushort* __restrict__ Wtl1, ushort* __restrict__ Wtl2) {
  int idx = blockIdx.x * 256 + threadIdx.x;   // 0..9215
  if (idx < 2048)        wprep_one(W1s, Wt1, 128, idx);
  else if (idx < 4096)   wprep_one(W2,  Wt2, 128, idx - 2048);
  else if (idx < 6144)   wprep_one(W3,  Wt3, 128, idx - 4096);
  else if (idx < 8192)   wprep_one(Wl1, Wtl1, 128, idx - 6144);
  else if (idx < 9216)   wprep_one(Wl2, Wtl2, 64, idx - 8192);
}

// ---------------- vd = W1d @ a1d (layer-1 dst attention vector) ----------------
__global__ __launch_bounds__(256) void make_vd_kernel(const float* __restrict__ Wd,
                                                      const float* __restrict__ ad_,
                                                      float* __restrict__ vd) {
  int gw = blockIdx.x * 4 + (threadIdx.x >> 6);   // 0..127
  int lane = threadIdx.x & 63;
  float2 w0 = ((const float2*)(Wd + gw * 128))[lane];
  float2 a0 = ((const float2*)ad_)[lane];
  float p = w0.x * a0.x + w0.y * a0.y;
  #pragma unroll
  for (int off = 32; off >= 1; off >>= 1) p += __shfl_down(p, off, 64);
  if (lane == 0) vd[gw] = p;
}

// ---------------- MFMA GEMM + fused alpha epilogue ----------------
// ALPHA: 0 = none; 1 = alpha_s & alpha_d from C accumulators (shared-W layers);
//        2 = alpha_s from C, alpha_d = x@adv fused into fp32 staging (layer 1).
template <int TN, bool RELU, bool HASBIAS, bool ABF16, bool OBF16, int ALPHA>
__global__ __launch_bounds__(256) void mfma_gemm_kernel(const void* __restrict__ Av,
                                                        const ushort* __restrict__ Wt,
                                                        const float* __restrict__ bias,
                                                        void* __restrict__ Cv, int n,
                                                        const float* __restrict__ asv,
                                                        const float* __restrict__ adv,
                                                        float* __restrict__ alpha_s,
                                                        float* __restrict__ alpha_d) {
  constexpr int WCOLS = TN / 2;
  constexpr int FI = 4;
  constexpr int FJ = WCOLS / 16;
  __shared__ char lds[32768 + TN * 256];
  ushort* sA = (ushort*)lds;
  ushort* sW = (ushort*)(lds + 32768);

  const int t = threadIdx.x;
  const int row0 = blockIdx.x * 128;
  const int lane = t & 63;
  const int wid = t >> 6;
  const int wr = wid >> 1, wc = wid & 1;

  float4 vd0, vd1;
  if constexpr (ALPHA == 2) {
    vd0 = ((const float4*)adv)[(t & 15) * 2];
    vd1 = ((const float4*)adv)[(t & 15) * 2 + 1];
  }

  #pragma unroll
  for (int i = 0; i < 8; ++i) {
    int r = i * 16 + (t >> 4);
    int c = t & 15;
    int gr = row0 + r;
    ushort8 o = 0;
    if (ABF16) {
      const ushort* Ab = (const ushort*)Av;
      if (gr < n) o = *(const ushort8*)(Ab + (size_t)gr * 128 + c * 8);
    } else {
      const float* A = (const float*)Av;
      float4 v0 = make_float4(0.f, 0.f, 0.f, 0.f), v1 = v0;
      if (gr < n) {
        const float4* Ar = (const float4*)(A + (size_t)gr * 128);
        v0 = Ar[c * 2];
        v1 = Ar[c * 2 + 1];
      }
      if constexpr (ALPHA == 2) {
        float pd = v0.x * vd0.x + v0.y * vd0.y + v0.z * vd0.z + v0.w * vd0.w
                 + v1.x * vd1.x + v1.y * vd1.y + v1.z * vd1.z + v1.w * vd1.w;
        pd += __shfl_xor(pd, 1, 64);
        pd += __shfl_xor(pd, 2, 64);
        pd += __shfl_xor(pd, 4, 64);
        pd += __shfl_xor(pd, 8, 64);
        if ((t & 15) == 0 && gr < n) alpha_d[gr] = pd;
      }
      o[0] = f2bf_rne(v0.x); o[1] = f2bf_rne(v0.y); o[2] = f2bf_rne(v0.z); o[3] = f2bf_rne(v0.w);
      o[4] = f2bf_rne(v1.x); o[5] = f2bf_rne(v1.y); o[6] = f2bf_rne(v1.z); o[7] = f2bf_rne(v1.w);
    }
    *(ushort8*)(sA + r * 128 + ((c ^ (r & 7)) * 8)) = o;
  }
  #pragma unroll
  for (int i = 0; i < TN / 16; ++i) {
    int chunk = i * 256 + t;
    *(ushort8*)(sW + chunk * 8) = *(const ushort8*)(Wt + chunk * 8);
  }
  __syncthreads();

  f32x4 acc[FI][FJ] = {};
  const int lm = lane & 15, q = lane >> 4, l7 = lane & 7;

  #pragma unroll
  for (int kk = 0; kk < 4; ++kk) {
    const int cs = kk * 4 + q;
    short8 af[FI], bfr[FJ];
    #pragma unroll
    for (int i = 0; i < FI; ++i) {
      int r = wr * 64 + i * 16 + lm;
      af[i] = *(const short8*)(sA + r * 128 + ((cs ^ l7) * 8));
    }
    #pragma unroll
    for (int j = 0; j < FJ; ++j) {
      int nn = wc * WCOLS + j * 16 + lm;
      bfr[j] = *(const short8*)(sW + nn * 128 + ((cs ^ l7) * 8));
    }
    #pragma unroll
    for (int i = 0; i < FI; ++i)
      #pragma unroll
      for (int j = 0; j < FJ; ++j)
        acc[i][j] = __builtin_amdgcn_mfma_f32_16x16x32_bf16(af[i], bfr[j], acc[i][j], 0, 0, 0);
  }

  #pragma unroll
  for (int i = 0; i < FI; ++i) {
    #pragma unroll
    for (int j = 0; j < FJ; ++j) {
      int gcol = wc * WCOLS + j * 16 + lm;
      float bv = HASBIAS ? bias[gcol] : 0.f;
      #pragma unroll
      for (int r = 0; r < 4; ++r) {
        int grow = row0 + wr * 64 + i * 16 + q * 4 + r;
        if (grow < n) {
          float v = acc[i][j][r] + bv;
          if (RELU) v = fmaxf(v, 0.f);
          if (OBF16) ((ushort*)Cv)[(size_t)grow * TN + gcol] = f2bf_rne(v);
          else       ((float*)Cv)[(size_t)grow * TN + gcol] = v;
        }
      }
    }
  }

  // ---- fused alpha epilogue (reuses sA region of LDS after sync) ----
  if constexpr (ALPHA >= 1) {
    __syncthreads();                     // all LDS reads for MFMA complete
    float* srs = (float*)lds;            // [128][2] alpha_s partials per wc
    float* srd = (float*)lds + 256;      // [128][2] alpha_d partials per wc
    float asl[FJ], adl[FJ];
    #pragma unroll
    for (int j = 0; j < FJ; ++j) {
      int gcol = wc * WCOLS + j * 16 + lm;
      asl[j] = asv[gcol];
      if constexpr (ALPHA == 1) adl[j] = adv[gcol];
    }
    #pragma unroll
    for (int i = 0; i < FI; ++i) {
      #pragma unroll
      for (int r = 0; r < 4; ++r) {
        float ps = 0.f, pdp = 0.f;
        #pragma unroll
        for (int j = 0; j < FJ; ++j) {
          ps = fmaf(acc[i][j][r], asl[j], ps);
          if constexpr (ALPHA == 1) pdp = fmaf(acc[i][j][r], adl[j], pdp);
        }
        ps += __shfl_xor(ps, 1, 64); ps += __shfl_xor(ps, 2, 64);
        ps += __shfl_xor(ps, 4, 64); ps += __shfl_xor(ps, 8, 64);
        if constexpr (ALPHA == 1) {
          pdp += __shfl_xor(pdp, 1, 64); pdp += __shfl_xor(pdp, 2, 64);
          pdp += __shfl_xor(pdp, 4, 64); pdp += __shfl_xor(pdp, 8, 64);
        }
        if (lm == 0) {
          int rl = wr * 64 + i * 16 + q * 4 + r;
          srs[rl * 2 + wc] = ps;
          if constexpr (ALPHA == 1) srd[rl * 2 + wc] = pdp;
        }
      }
    }
    __syncthreads();
    if (t < 128) {
      int grow = row0 + t;
      if (grow < n) {
        alpha_s[grow] = srs[t * 2] + srs[t * 2 + 1];
        if constexpr (ALPHA == 1) alpha_d[grow] = srd[t * 2] + srd[t * 2 + 1];
      }
    }
  }
}

// ---------------- per-edge records: erec[j] = (src, exp(lrelu(as+ad))) ----------------
__global__ void edge_p_kernel(const int* __restrict__ row_ptr, const int* __restrict__ src_sorted,
                              const float* __restrict__ alpha_s, const float* __restrict__ alpha_d,
                              uint2* __restrict__ erec, int n) {
  int wid = blockIdx.x * (blockDim.x >> 6) + (threadIdx.x >> 6);
  int lane = threadIdx.x & 63;
  int node = wid * 4 + (lane >> 4);
  if (node >= n) return;
  int beg = row_ptr[node], end = row_ptr[node + 1];
  float ad = alpha_d[node];
  for (int j = beg + (lane & 15); j < end; j += 16) {
    int u = src_sorted[j];
    float e = alpha_s[u] + ad;
    e = (e > 0.f) ? e : 0.2f * e;
    erec[j] = make_uint2((uint)u, __float_as_uint(__expf(e)));
  }
}

// ---------------- GAT aggregation: 2 nodes per wave, 8B/lane gathers ----------
__global__ void gat_aggregate_kernel(const uint2* __restrict__ hs2,
                                     const uint2* __restrict__ erec,
                                     const int* __restrict__ row_ptr,
                                     const float* __restrict__ bias,
                                     uint2* __restrict__ outb, int n) {
  const int t = threadIdx.x;
  const int pairw = blockIdx.x * 4 + (t >> 6);   // wave index
  const int lane = t & 63;
  const int half = lane >> 5;
  const int sl = lane & 31;
  const int node = pairw * 2 + half;
  const bool active = node < n;
  const int beg = active ? row_ptr[node] : 0;
  const int end = active ? row_ptr[node + 1] : 0;

  float sA = 0.f, sB = 0.f;
  float Ax0 = 0.f, Ay0 = 0.f, Ax1 = 0.f, Ay1 = 0.f;
  float Bx0 = 0.f, By0 = 0.f, Bx1 = 0.f, By1 = 0.f;

  int j = beg;
  for (; j + 4 <= end; j += 4) {
    uint4 eA = *(const uint4*)&erec[j];
    uint4 eB = *(const uint4*)&erec[j + 2];
    uint2 h0 = hs2[(size_t)eA.x * 32 + sl];
    uint2 h1 = hs2[(size_t)eA.z * 32 + sl];
    uint2 h2 = hs2[(size_t)eB.x * 32 + sl];
    uint2 h3 = hs2[(size_t)eB.z * 32 + sl];
    float p0 = __uint_as_float(eA.y), p1 = __uint_as_float(eA.w);
    float p2 = __uint_as_float(eB.y), p3 = __uint_as_float(eB.w);
    sA += p0 + p1;
    sB += p2 + p3;
    Ax0 = fmaf(p0, __uint_as_float(h0.x << 16), Ax0);
    Ay0 = fmaf(p0, __uint_as_float(h0.x & 0xFFFF0000u), Ay0);
    Ax1 = fmaf(p0, __uint_as_float(h0.y << 16), Ax1);
    Ay1 = fmaf(p0, __uint_as_float(h0.y & 0xFFFF0000u), Ay1);
    Bx0 = fmaf(p1, __uint_as_float(h1.x << 16), Bx0);
    By0 = fmaf(p1, __uint_as_float(h1.x & 0xFFFF0000u), By0);
    Bx1 = fmaf(p1, __uint_as_float(h1.y << 16), Bx1);
    By1 = fmaf(p1, __uint_as_float(h1.y & 0xFFFF0000u), By1);
    Ax0 = fmaf(p2, __uint_as_float(h2.x << 16), Ax0);
    Ay0 = fmaf(p2, __uint_as_float(h2.x & 0xFFFF0000u), Ay0);
    Ax1 = fmaf(p2, __uint_as_float(h2.y << 16), Ax1);
    Ay1 = fmaf(p2, __uint_as_float(h2.y & 0xFFFF0000u), Ay1);
    Bx0 = fmaf(p3, __uint_as_float(h3.x << 16), Bx0);
    By0 = fmaf(p3, __uint_as_float(h3.x & 0xFFFF0000u), By0);
    Bx1 = fmaf(p3, __uint_as_float(h3.y << 16), Bx1);
    By1 = fmaf(p3, __uint_as_float(h3.y & 0xFFFF0000u), By1);
  }
  for (; j < end; ++j) {
    uint2 r = erec[j];
    float p = __uint_as_float(r.y);
    uint2 h = hs2[(size_t)r.x * 32 + sl];
    sA += p;
    Ax0 = fmaf(p, __uint_as_float(h.x << 16), Ax0);
    Ay0 = fmaf(p, __uint_as_float(h.x & 0xFFFF0000u), Ay0);
    Ax1 = fmaf(p, __uint_as_float(h.y << 16), Ax1);
    Ay1 = fmaf(p, __uint_as_float(h.y & 0xFFFF0000u), Ay1);
  }

  if (active) {
    float s = sA + sB;
    float inv = 1.f / (s + 1e-16f);
    float4 bv = ((const float4*)bias)[sl];
    float o0 = fmaxf(fmaf(Ax0 + Bx0, inv, bv.x), 0.f);
    float o1 = fmaxf(fmaf(Ay0 + By0, inv, bv.y), 0.f);
    float o2 = fmaxf(fmaf(Ax1 + Bx1, inv, bv.z), 0.f);
    float o3 = fmaxf(fmaf(Ay1 + By1, inv, bv.w), 0.f);
    uint2 pk;
    pk.x = ((uint)f2bf_rne(o1) << 16) | (uint)f2bf_rne(o0);
    pk.y = ((uint)f2bf_rne(o3) << 16) | (uint)f2bf_rne(o2);
    outb[(size_t)node * 32 + sl] = pk;
  }
}

// ---------------------------------------------------------------------------
extern "C" void kernel_launch(void* const* d_in, const int* in_sizes, int n_in,
                              void* d_out, int out_size, void* d_ws, size_t ws_size,
                              hipStream_t stream) {
  const float* x     = (const float*)d_in[0];
  const int*   eidx  = (const int*)d_in[1];
  const float* W1s   = (const float*)d_in[2];
  const float* W1d   = (const float*)d_in[3];
  const float* a1s   = (const float*)d_in[4];
  const float* a1d   = (const float*)d_in[5];
  const float* b1    = (const float*)d_in[6];
  const float* W2    = (const float*)d_in[7];
  const float* a2s   = (const float*)d_in[8];
  const float* a2d   = (const float*)d_in[9];
  const float* b2    = (const float*)d_in[10];
  const float* W3    = (const float*)d_in[11];
  const float* a3s   = (const float*)d_in[12];
  const float* a3d   = (const float*)d_in[13];
  const float* b3    = (const float*)d_in[14];
  const float* Wl1   = (const float*)d_in[15];
  const float* bl1   = (const float*)d_in[16];
  const float* Wl2   = (const float*)d_in[17];
  const float* bl2   = (const float*)d_in[18];
  float* out = (float*)d_out;

  const int N = in_sizes[0] / 128;
  const int E = in_sizes[1] / 2;
  const int* src = eidx;
  const int* dst = eidx + E;
  const int NB = (N + 511) >> 9;

  // ---- workspace layout ----
  char* base = (char*)d_ws;
  size_t off = 0;
  auto alloc = [&](size_t bytes) -> void* {
    void* p = base + off;
    off += (bytes + 511) & ~(size_t)511;
    return p;
  };
  uint*  Pb       = (uint*)alloc((size_t)N * 128 * 2);   // layer io, packed bf16
  uint*  Qb       = (uint*)alloc((size_t)N * 128 * 2);   // messages, packed bf16
  char*  Q2reg    = (char*)alloc((size_t)N * 128 * 4);   // buckets/erec/Q2b region
  uint*  buckets  = (uint*)Q2reg;                        // dead before head
  uint2* erec     = (uint2*)(Q2reg + ((size_t)24 << 20));// dead before head
  ushort* Q2b     = (ushort*)Q2reg;                      // head hidden, bf16
  float* alpha_s  = (float*)alloc((size_t)N * 4);
  float* alpha_d  = (float*)alloc((size_t)N * 4);
  float* vd       = (float*)alloc(128 * 4);
  int* row_ptr    = (int*)alloc((size_t)(N + 1) * 4);
  int* bcount     = (int*)alloc(256 * 4);
  int* bbase      = (int*)alloc(256 * 4);
  int* src_sorted = (int*)alloc((size_t)E * 4);
  ushort* Wt1     = (ushort*)alloc(128 * 128 * 2);
  ushort* Wt2     = (ushort*)alloc(128 * 128 * 2);
  ushort* Wt3     = (ushort*)alloc(128 * 128 * 2);
  ushort* Wtl1    = (ushort*)alloc(128 * 128 * 2);
  ushort* Wtl2    = (ushort*)alloc(64 * 128 * 2);
  (void)ws_size;

  const int TB = 256;
  const int ggrid = (N + 127) / 128;
  const int pagrid = (E + PA_CHUNK - 1) / PA_CHUNK;
  const int epgrid = (N + 15) / 16;
  const int aggrid = (N + 7) / 8;            // 4 waves/block, 2 nodes/wave

  // ---- CSR build ----
  hipMemsetAsync(bcount, 0, 256 * 4, stream);
  bucket_scatter_kernel<<<pagrid, 256, 0, stream>>>(src, dst, bcount, buckets, E, NB);
  scan_buckets_kernel<<<1, 256, 0, stream>>>(bcount, bbase, NB, row_ptr, N, E);
  bucket_sort_kernel<<<NB, 256, 0, stream>>>(buckets, bcount, bbase, row_ptr, src_sorted, N);

  // ---- weight prep + layer-1 vd (one small launch each) ----
  wprep_all_kernel<<<36, 256, 0, stream>>>(W1s, W2, W3, Wl1, Wl2,
                                           Wt1, Wt2, Wt3, Wtl1, Wtl2);
  make_vd_kernel<<<32, 256, 0, stream>>>(W1d, a1d, vd);

  // ---- layer 1: x -> Pb (GEMM computes Qb + alpha_s + alpha_d) ----
  mfma_gemm_kernel<128, false, false, false, true, 2><<<ggrid, 256, 0, stream>>>(
      x, Wt1, nullptr, Qb, N, a1s, vd, alpha_s, alpha_d);
  edge_p_kernel<<<epgrid, TB, 0, stream>>>(row_ptr, src_sorted, alpha_s, alpha_d, erec, N);
  gat_aggregate_kernel<<<aggrid, TB, 0, stream>>>((const uint2*)Qb, erec, row_ptr, b1, (uint2*)Pb, N);

  // ---- layer 2: Pb -> Pb ----
  mfma_gemm_kernel<128, false, false, true, true, 1><<<ggrid, 256, 0, stream>>>(
      Pb, Wt2, nullptr, Qb, N, a2s, a2d, alpha_s, alpha_d);
  edge_p_kernel<<<epgrid, TB, 0, stream>>>(row_ptr, src_sorted, alpha_s, alpha_d, erec, N);
  gat_aggregate_kernel<<<aggrid, TB, 0, stream>>>((const uint2*)Qb, erec, row_ptr, b2, (uint2*)Pb, N);

  // ---- layer 3: Pb -> Pb ----
  mfma_gemm_kernel<128, false, false, true, true, 1><<<ggrid, 256, 0, stream>>>(
      Pb, Wt3, nullptr, Qb, N, a3s, a3d, alpha_s, alpha_d);
  edge_p_kernel<<<epgrid, TB, 0, stream>>>(row_ptr, src_sorted, alpha_s, alpha_d, erec, N);
  gat_aggregate_kernel<<<aggrid, TB, 0, stream>>>((const uint2*)Qb, erec, row_ptr, b3, (uint2*)Pb, N);

  // ---- MLP head (buckets/erec dead; Q2b reuses the region) ----
  mfma_gemm_kernel<128, true, true, true, true, 0><<<ggrid, 256, 0, stream>>>(
      Pb, Wtl1, bl1, Q2b, N, nullptr, nullptr, nullptr, nullptr);
  mfma_gemm_kernel<64, false, true, true, false, 0><<<ggrid, 256, 0, stream>>>(
      Q2b, Wtl2, bl2, out, N, nullptr, nullptr, nullptr, nullptr);
}